// Round 3
// baseline (681.474 us; speedup 1.0000x reference)
//
#include <hip/hip_runtime.h>
#include <hip/hip_bf16.h>
#include <cstdint>
#include <cstddef>

#define NB 4
#define SS 2048
#define DMODEL 512
#define NH 8
#define DKK 64

typedef __attribute__((ext_vector_type(8))) short short8;
typedef __attribute__((ext_vector_type(8))) unsigned short ushort8;
typedef __attribute__((ext_vector_type(4))) float f32x4;

static __device__ __forceinline__ unsigned short f2bf(float f){
  unsigned int u = __float_as_uint(f);
  u += 0x7fff + ((u >> 16) & 1);   // round-to-nearest-even
  return (unsigned short)(u >> 16);
}

static __device__ __forceinline__ f32x4 mfma16(short8 a, short8 b, f32x4 c){
  return __builtin_amdgcn_mfma_f32_16x16x32_bf16(a, b, c, 0, 0, 0);
}

// ---------------------------------------------------------------------------
// Weight prep: wq_t/wk_t[col][d] bf16 (col = h*64+n), wv unused here (VALU vs).
// ---------------------------------------------------------------------------
__global__ __launch_bounds__(256) void prep_w(const float* __restrict__ Wq,
    const float* __restrict__ Wk,
    unsigned short* __restrict__ wq_t, unsigned short* __restrict__ wk_t){
  int i = blockIdx.x*256 + threadIdx.x;
  if (i < 512*512){
    int col = i >> 9, d = i & 511;
    int src = (col >> 6)*(512*64) + d*64 + (col & 63);
    wq_t[i] = f2bf(Wq[src]);
    wk_t[i] = f2bf(Wk[src]);
  }
}

// ---------------------------------------------------------------------------
// Projection GEMM for Q/K: out[h][b][s][n] = bf16( A[b,s,:] @ W[h,:,n] )
// (m97-pattern fragment mappings, HW-verified C-layout)
// ---------------------------------------------------------------------------
__global__ __launch_bounds__(256) void proj_qk(const float* __restrict__ A,
    const unsigned short* __restrict__ Wt, unsigned short* __restrict__ outb){
  const int m0 = blockIdx.x*64;
  const int h  = blockIdx.y;
  __shared__ alignas(16) unsigned short Alds[64][40];
  __shared__ alignas(16) unsigned short Wlds[64][40];
  const int t = threadIdx.x, w = t>>6, l = t&63;
  const int srow = t>>2, sk0 = (t&3)*8;
  f32x4 acc[4] = {{0,0,0,0},{0,0,0,0},{0,0,0,0},{0,0,0,0}};
  for (int ks=0; ks<512; ks+=32){
    const float* asrc = A + (size_t)(m0+srow)*512 + ks + sk0;
    f32x4 f0 = *(const f32x4*)asrc;
    f32x4 f1 = *(const f32x4*)(asrc+4);
    ushort8 av;
    av[0]=f2bf(f0[0]); av[1]=f2bf(f0[1]); av[2]=f2bf(f0[2]); av[3]=f2bf(f0[3]);
    av[4]=f2bf(f1[0]); av[5]=f2bf(f1[1]); av[6]=f2bf(f1[2]); av[7]=f2bf(f1[3]);
    ushort8 wv8 = *(const ushort8*)(Wt + (size_t)(h*64+srow)*512 + ks + sk0);
    __syncthreads();
    *(ushort8*)&Alds[srow][sk0] = av;
    *(ushort8*)&Wlds[srow][sk0] = wv8;
    __syncthreads();
    short8 a = *(const short8*)&Alds[w*16 + (l&15)][(l>>4)*8];
    #pragma unroll
    for (int nt=0; nt<4; nt++){
      short8 b = *(const short8*)&Wlds[nt*16 + (l&15)][(l>>4)*8];
      acc[nt] = mfma16(a, b, acc[nt]);
    }
  }
  #pragma unroll
  for (int nt=0; nt<4; nt++){
    #pragma unroll
    for (int r=0; r<4; r++){
      int m = m0 + w*16 + (l>>4)*4 + r;
      int b_ = m >> 11, s_ = m & 2047;
      outb[(((size_t)(h*NB + b_)*SS + s_)<<6) + nt*16 + (l&15)] = f2bf(acc[nt][r]);
    }
  }
}

// ---------------------------------------------------------------------------
// vs[b][s][dv] = v[b,s,:] @ Wv  -- pure f32 VALU, no layout cleverness.
// ---------------------------------------------------------------------------
__global__ __launch_bounds__(256) void vs_f32(const float* __restrict__ v,
    const float* __restrict__ Wv, float* __restrict__ vs){
  __shared__ float vrow[4][512];
  const int t = threadIdx.x;
  const int M = blockIdx.x*4;   // global row in [0,8192)
  for (int i = t; i < 4*512; i += 256)
    vrow[i>>9][i&511] = v[(size_t)(M + (i>>9))*512 + (i&511)];
  __syncthreads();
  const int r = t>>6, dv = t&63;
  float acc = 0.f;
  for (int d = 0; d < 512; d++)
    acc += vrow[r][d] * Wv[d*64 + dv];
  vs[(size_t)(M + r)*64 + dv] = acc;
}

// ---------------------------------------------------------------------------
// Pass 1: per-row sum of exp(score*scale) over all K  ->  rinv = 1/sum.
// ---------------------------------------------------------------------------
__global__ __launch_bounds__(256) void attn_pass1(const unsigned short* __restrict__ qsb,
    const unsigned short* __restrict__ ksb, float* __restrict__ rinv){
  const int q0 = blockIdx.x*64, b_ = blockIdx.y, h = blockIdx.z;
  __shared__ alignas(16) unsigned short Qlds[64][72];
  __shared__ alignas(16) unsigned short Klds[64][72];
  const int t = threadIdx.x, w = t>>6, l = t&63;
  const int srow = t>>2, sc0 = (t&3)*16;
  const unsigned short* qsrc = qsb + (((size_t)(h*NB + b_)*SS + q0)<<6);
  const unsigned short* ksrc = ksb + (((size_t)(h*NB + b_)*SS)<<6);
  {
    const ushort8* s0 = (const ushort8*)(qsrc + srow*64 + sc0);
    *(ushort8*)&Qlds[srow][sc0]   = s0[0];
    *(ushort8*)&Qlds[srow][sc0+8] = s0[1];
  }
  float rsum[4] = {0.f,0.f,0.f,0.f};
  for (int kt=0; kt<32; kt++){
    ushort8 k0v = *(const ushort8*)(ksrc + ((size_t)(kt*64 + srow)<<6) + sc0);
    ushort8 k1v = *(const ushort8*)(ksrc + ((size_t)(kt*64 + srow)<<6) + sc0 + 8);
    __syncthreads();
    *(ushort8*)&Klds[srow][sc0]   = k0v;
    *(ushort8*)&Klds[srow][sc0+8] = k1v;
    __syncthreads();
    short8 a0 = *(const short8*)&Qlds[w*16 + (l&15)][(l>>4)*8];
    short8 a1 = *(const short8*)&Qlds[w*16 + (l&15)][32 + (l>>4)*8];
    #pragma unroll
    for (int nt=0; nt<4; nt++){
      short8 b0 = *(const short8*)&Klds[nt*16 + (l&15)][(l>>4)*8];
      short8 b1 = *(const short8*)&Klds[nt*16 + (l&15)][32 + (l>>4)*8];
      f32x4 acc = {0.f,0.f,0.f,0.f};
      acc = mfma16(a0, b0, acc);
      acc = mfma16(a1, b1, acc);
      #pragma unroll
      for (int r=0; r<4; r++) rsum[r] += __expf(acc[r]*0.125f);
    }
  }
  #pragma unroll
  for (int r=0; r<4; r++){
    float v = rsum[r];
    v += __shfl_xor(v, 1); v += __shfl_xor(v, 2);
    v += __shfl_xor(v, 4); v += __shfl_xor(v, 8);
    rsum[r] = v;
  }
  if ((l & 15) == 0){
    float* dst = rinv + (size_t)(h*NB + b_)*SS + q0 + w*16 + (l>>4)*4;
    #pragma unroll
    for (int r=0; r<4; r++) dst[r] = 1.0f/rsum[r];
  }
}

// ---------------------------------------------------------------------------
// Pass 2 (lite): recompute scores, write normalized attn (f32). No PV here.
// ---------------------------------------------------------------------------
__global__ __launch_bounds__(256) void attn_pass2(const unsigned short* __restrict__ qsb,
    const unsigned short* __restrict__ ksb,
    const float* __restrict__ rinv, float* __restrict__ attn){
  const int q0 = blockIdx.x*64, b_ = blockIdx.y, h = blockIdx.z;
  __shared__ alignas(16) unsigned short Qlds[64][72];
  __shared__ alignas(16) unsigned short Klds[64][72];
  const int t = threadIdx.x, w = t>>6, l = t&63;
  const int srow = t>>2, sc0 = (t&3)*16;
  const unsigned short* qsrc = qsb + (((size_t)(h*NB + b_)*SS + q0)<<6);
  const unsigned short* ksrc = ksb + (((size_t)(h*NB + b_)*SS)<<6);
  {
    const ushort8* s0 = (const ushort8*)(qsrc + srow*64 + sc0);
    *(ushort8*)&Qlds[srow][sc0]   = s0[0];
    *(ushort8*)&Qlds[srow][sc0+8] = s0[1];
  }
  float ri[4];
  {
    const float* rp = rinv + (size_t)(h*NB + b_)*SS + q0 + w*16 + (l>>4)*4;
    #pragma unroll
    for (int r=0;r<4;r++) ri[r] = rp[r];
  }
  float* arow = attn + (size_t)(h*NB + b_)*SS*SS + (size_t)q0*SS;
  for (int kt=0; kt<32; kt++){
    ushort8 k0v = *(const ushort8*)(ksrc + ((size_t)(kt*64 + srow)<<6) + sc0);
    ushort8 k1v = *(const ushort8*)(ksrc + ((size_t)(kt*64 + srow)<<6) + sc0 + 8);
    __syncthreads();
    *(ushort8*)&Klds[srow][sc0]   = k0v;
    *(ushort8*)&Klds[srow][sc0+8] = k1v;
    __syncthreads();
    short8 a0 = *(const short8*)&Qlds[w*16 + (l&15)][(l>>4)*8];
    short8 a1 = *(const short8*)&Qlds[w*16 + (l&15)][32 + (l>>4)*8];
    #pragma unroll
    for (int nt=0; nt<4; nt++){
      short8 b0 = *(const short8*)&Klds[nt*16 + (l&15)][(l>>4)*8];
      short8 b1 = *(const short8*)&Klds[nt*16 + (l&15)][32 + (l>>4)*8];
      f32x4 acc = {0.f,0.f,0.f,0.f};
      acc = mfma16(a0, b0, acc);
      acc = mfma16(a1, b1, acc);
      #pragma unroll
      for (int r=0; r<4; r++){
        float p = __expf(acc[r]*0.125f) * ri[r];
        arow[(size_t)(w*16 + (l>>4)*4 + r)*SS + kt*64 + nt*16 + (l&15)] = p;
      }
    }
  }
}

// ---------------------------------------------------------------------------
// mh[b][q][dv] = (1/8) * sum_s (sum_h attn[h][b][q][s]) * vs[b][s][dv]
// Pure VALU, reads attn straight from the validated output buffer.
// ---------------------------------------------------------------------------
__global__ __launch_bounds__(256) void pv_mean(const float* __restrict__ attn,
    const float* __restrict__ vs, float* __restrict__ mh){
  const int qq = blockIdx.x, b_ = blockIdx.y;
  __shared__ float abar[2048];
  __shared__ float red[4][64];
  const int t = threadIdx.x;
  for (int s = t; s < 2048; s += 256){
    float a = 0.f;
    #pragma unroll
    for (int h = 0; h < 8; h++)
      a += attn[((size_t)(h*NB + b_)*SS + qq)*SS + s];
    abar[s] = a;
  }
  __syncthreads();
  const int dv = t & 63, c = t >> 6;
  const float* vsb = vs + (size_t)b_*SS*64;
  float p = 0.f;
  for (int s = c*512; s < c*512 + 512; s++)
    p += abar[s] * vsb[(size_t)s*64 + dv];
  red[c][dv] = p;
  __syncthreads();
  if (t < 64){
    float m = (red[0][t] + red[1][t] + red[2][t] + red[3][t]) * 0.125f;
    mh[((size_t)b_*SS + qq)*64 + t] = m;
  }
}

// ---------------------------------------------------------------------------
// Final: out[b,s,:] = mh[b,s,:] @ Wo[64,512]
// ---------------------------------------------------------------------------
__global__ __launch_bounds__(256) void final_out(const float* __restrict__ mh,
    const float* __restrict__ Wo, float* __restrict__ out){
  __shared__ alignas(16) float mlds[32][68];
  const int t = threadIdx.x;
  const int m0 = blockIdx.x*32;
  {
    int row = t>>3, k0 = (t&7)*8;
    const f32x4* src = (const f32x4*)(mh + (size_t)(m0+row)*64 + k0);
    *(f32x4*)&mlds[row][k0]   = src[0];
    *(f32x4*)&mlds[row][k0+4] = src[1];
  }
  __syncthreads();
  const int mrow = t>>3, n0 = (t&7)*64;
  f32x4 zero = {0.f,0.f,0.f,0.f};
  f32x4 a4[16];
  #pragma unroll
  for (int j=0;j<16;j++) a4[j] = zero;
  for (int k=0; k<64; k++){
    float am = mlds[mrow][k];
    const f32x4* wo4 = (const f32x4*)(Wo + (size_t)k*512 + n0);
    #pragma unroll
    for (int j=0; j<16; j++) a4[j] += am * wo4[j];
  }
  float* dst = out + (size_t)(m0+mrow)*512 + n0;
  #pragma unroll
  for (int j=0; j<16; j++) *(f32x4*)(dst + j*4) = a4[j];
}

// ---------------------------------------------------------------------------
// Scratch plan (de-risks unknown ws_size):
//   d_out head  [0 .. 16.8MB)       : qs_buf | ks_buf   (dead before final_out writes)
//   attn tail   [last 1.05MB of attn): wq_t | wk_t      (dead before pass2 overwrites)
//   d_ws (4.3MB): rinv | vs | mh
// ---------------------------------------------------------------------------
extern "C" void kernel_launch(void* const* d_in, const int* in_sizes, int n_in,
                              void* d_out, int out_size, void* d_ws, size_t ws_size,
                              hipStream_t stream){
  (void)in_sizes; (void)n_in; (void)out_size; (void)ws_size;
  const float* q  = (const float*)d_in[0];
  const float* k  = (const float*)d_in[1];
  const float* v  = (const float*)d_in[2];
  const float* Wq = (const float*)d_in[3];
  const float* Wk = (const float*)d_in[4];
  const float* Wv = (const float*)d_in[5];
  const float* Wo = (const float*)d_in[6];
  float* out  = (float*)d_out;
  float* attn = out + (size_t)NB*SS*DMODEL;   // outputs concatenated: out, attn

  // scratch in d_out head: qs (4,194,304 ushort) + ks (4,194,304 ushort) = 16,777,216 B
  unsigned short* qs_buf = (unsigned short*)d_out;
  unsigned short* ks_buf = qs_buf + (size_t)NH*NB*SS*DKK;
  // bf16 weights at the very tail of the attn region (overwritten later by pass2)
  unsigned short* w_tail = (unsigned short*)(attn + (size_t)NH*NB*SS*SS) - (262144 + 262144);
  unsigned short* wq_t = w_tail;
  unsigned short* wk_t = w_tail + 262144;
  // d_ws: rinv 256KB | vs 2MB | mh 2MB
  float* rinv = (float*)d_ws;
  float* vs   = (float*)((char*)d_ws + 262144);
  float* mh   = (float*)((char*)d_ws + 262144 + 2097152);

  prep_w<<<dim3(1024), 256, 0, stream>>>(Wq, Wk, wq_t, wk_t);
  proj_qk<<<dim3(128, 8), 256, 0, stream>>>(q, wq_t, qs_buf);
  proj_qk<<<dim3(128, 8), 256, 0, stream>>>(k, wk_t, ks_buf);
  vs_f32<<<dim3(2048), 256, 0, stream>>>(v, Wv, vs);
  attn_pass1<<<dim3(32, NB, NH), 256, 0, stream>>>(qs_buf, ks_buf, rinv);
  attn_pass2<<<dim3(32, NB, NH), 256, 0, stream>>>(qs_buf, ks_buf, rinv, attn);
  pv_mean<<<dim3(SS, NB), 256, 0, stream>>>(attn, vs, mh);
  final_out<<<dim3(256), 256, 0, stream>>>(mh, Wo, out);
}

// Round 6
// 600.857 us; speedup vs baseline: 1.1342x; 1.1342x over previous
//
#include <hip/hip_runtime.h>
#include <hip/hip_bf16.h>
#include <cstdint>
#include <cstddef>

#define NB 4
#define SS 2048
#define DMODEL 512
#define NH 8
#define DKK 64

typedef __attribute__((ext_vector_type(8))) short short8;
typedef __attribute__((ext_vector_type(8))) unsigned short ushort8;
typedef __attribute__((ext_vector_type(4))) float f32x4;

static __device__ __forceinline__ unsigned short f2bf(float f){
  unsigned int u = __float_as_uint(f);
  u += 0x7fff + ((u >> 16) & 1);   // round-to-nearest-even
  return (unsigned short)(u >> 16);
}

static __device__ __forceinline__ f32x4 mfma16(short8 a, short8 b, f32x4 c){
  return __builtin_amdgcn_mfma_f32_16x16x32_bf16(a, b, c, 0, 0, 0);
}

// ---------------------------------------------------------------------------
// Weight prep: wq_t/wk_t[col][d] bf16 (col = h*64+n), wv_t[n][d] bf16 (unused
// this round; slot kept to hold layout constant).
// ---------------------------------------------------------------------------
__global__ __launch_bounds__(256) void prep_w(const float* __restrict__ Wq,
    const float* __restrict__ Wk, const float* __restrict__ Wv,
    unsigned short* __restrict__ wq_t, unsigned short* __restrict__ wk_t,
    unsigned short* __restrict__ wv_t){
  int i = blockIdx.x*256 + threadIdx.x;
  if (i < 512*512){
    int col = i >> 9, d = i & 511;
    int src = (col >> 6)*(512*64) + d*64 + (col & 63);
    wq_t[i] = f2bf(Wq[src]);
    wk_t[i] = f2bf(Wk[src]);
  } else {
    int j = i - 512*512;
    if (j < 64*512){
      int n = j >> 9, d = j & 511;
      wv_t[j] = f2bf(Wv[d*64 + n]);
    }
  }
}

// ---------------------------------------------------------------------------
// zero macc: 512 blocks x 256 threads x 4 floats = 524,288 floats (exact).
// ---------------------------------------------------------------------------
__global__ __launch_bounds__(256) void zero_macc(float* __restrict__ macc){
  f32x4 z = {0.f,0.f,0.f,0.f};
  *(f32x4*)(macc + ((size_t)blockIdx.x*256 + threadIdx.x)*4) = z;
}

// ---------------------------------------------------------------------------
// Projection GEMM for Q/K: out[h][b][s][n] = bf16( A[b,s,:] @ W[h,:,n] )
// ---------------------------------------------------------------------------
__global__ __launch_bounds__(256) void proj_qk(const float* __restrict__ A,
    const unsigned short* __restrict__ Wt, unsigned short* __restrict__ outb){
  const int m0 = blockIdx.x*64;
  const int h  = blockIdx.y;
  __shared__ alignas(16) unsigned short Alds[64][40];
  __shared__ alignas(16) unsigned short Wlds[64][40];
  const int t = threadIdx.x, w = t>>6, l = t&63;
  const int srow = t>>2, sk0 = (t&3)*8;
  f32x4 acc[4] = {{0,0,0,0},{0,0,0,0},{0,0,0,0},{0,0,0,0}};
  for (int ks=0; ks<512; ks+=32){
    const float* asrc = A + (size_t)(m0+srow)*512 + ks + sk0;
    f32x4 f0 = *(const f32x4*)asrc;
    f32x4 f1 = *(const f32x4*)(asrc+4);
    ushort8 av;
    av[0]=f2bf(f0[0]); av[1]=f2bf(f0[1]); av[2]=f2bf(f0[2]); av[3]=f2bf(f0[3]);
    av[4]=f2bf(f1[0]); av[5]=f2bf(f1[1]); av[6]=f2bf(f1[2]); av[7]=f2bf(f1[3]);
    ushort8 wv8 = *(const ushort8*)(Wt + (size_t)(h*64+srow)*512 + ks + sk0);
    __syncthreads();
    *(ushort8*)&Alds[srow][sk0] = av;
    *(ushort8*)&Wlds[srow][sk0] = wv8;
    __syncthreads();
    short8 a = *(const short8*)&Alds[w*16 + (l&15)][(l>>4)*8];
    #pragma unroll
    for (int nt=0; nt<4; nt++){
      short8 b = *(const short8*)&Wlds[nt*16 + (l&15)][(l>>4)*8];
      acc[nt] = mfma16(a, b, acc[nt]);
    }
  }
  #pragma unroll
  for (int nt=0; nt<4; nt++){
    #pragma unroll
    for (int r=0; r<4; r++){
      int m = m0 + w*16 + (l>>4)*4 + r;
      int b_ = m >> 11, s_ = m & 2047;
      outb[(((size_t)(h*NB + b_)*SS + s_)<<6) + nt*16 + (l&15)] = f2bf(acc[nt][r]);
    }
  }
}

// ---------------------------------------------------------------------------
// vs[b][s][dv] = v[b,s,:] @ Wv  -- validated in round 3 (pure f32 VALU).
// ---------------------------------------------------------------------------
__global__ __launch_bounds__(256) void vs_f32(const float* __restrict__ v,
    const float* __restrict__ Wv, float* __restrict__ vs){
  __shared__ float vrow[4][512];
  const int t = threadIdx.x;
  const int M = blockIdx.x*4;   // global row in [0,8192)
  for (int i = t; i < 4*512; i += 256)
    vrow[i>>9][i&511] = v[(size_t)(M + (i>>9))*512 + (i&511)];
  __syncthreads();
  const int r = t>>6, dv = t&63;
  float acc = 0.f;
  for (int d = 0; d < 512; d++)
    acc += vrow[r][d] * Wv[d*64 + dv];
  vs[(size_t)(M + r)*64 + dv] = acc;
}

// ---------------------------------------------------------------------------
// Trivially-correct transpose: vst[b][dv][s] = bf16(vs[b][s][dv]).
// ---------------------------------------------------------------------------
__global__ __launch_bounds__(256) void transpose_v(const float* __restrict__ vs,
    unsigned short* __restrict__ vst){
  int idx = blockIdx.x*256 + threadIdx.x;      // 0 .. 524287
  int dv = idx & 63;
  int sg = idx >> 6;                           // global s-row 0..8191
  int b_ = sg >> 11, s_ = sg & 2047;
  vst[((size_t)(b_*64 + dv))*2048 + s_] = f2bf(vs[idx]);
}

// ---------------------------------------------------------------------------
// Pass 1: per-row sum of exp(score*scale) over all K  ->  rinv = 1/sum.
// ---------------------------------------------------------------------------
__global__ __launch_bounds__(256) void attn_pass1(const unsigned short* __restrict__ qsb,
    const unsigned short* __restrict__ ksb, float* __restrict__ rinv){
  const int q0 = blockIdx.x*64, b_ = blockIdx.y, h = blockIdx.z;
  __shared__ alignas(16) unsigned short Qlds[64][72];
  __shared__ alignas(16) unsigned short Klds[64][72];
  const int t = threadIdx.x, w = t>>6, l = t&63;
  const int srow = t>>2, sc0 = (t&3)*16;
  const unsigned short* qsrc = qsb + (((size_t)(h*NB + b_)*SS + q0)<<6);
  const unsigned short* ksrc = ksb + (((size_t)(h*NB + b_)*SS)<<6);
  {
    const ushort8* s0 = (const ushort8*)(qsrc + srow*64 + sc0);
    *(ushort8*)&Qlds[srow][sc0]   = s0[0];
    *(ushort8*)&Qlds[srow][sc0+8] = s0[1];
  }
  float rsum[4] = {0.f,0.f,0.f,0.f};
  for (int kt=0; kt<32; kt++){
    ushort8 k0v = *(const ushort8*)(ksrc + ((size_t)(kt*64 + srow)<<6) + sc0);
    ushort8 k1v = *(const ushort8*)(ksrc + ((size_t)(kt*64 + srow)<<6) + sc0 + 8);
    __syncthreads();
    *(ushort8*)&Klds[srow][sc0]   = k0v;
    *(ushort8*)&Klds[srow][sc0+8] = k1v;
    __syncthreads();
    short8 a0 = *(const short8*)&Qlds[w*16 + (l&15)][(l>>4)*8];
    short8 a1 = *(const short8*)&Qlds[w*16 + (l&15)][32 + (l>>4)*8];
    #pragma unroll
    for (int nt=0; nt<4; nt++){
      short8 b0 = *(const short8*)&Klds[nt*16 + (l&15)][(l>>4)*8];
      short8 b1 = *(const short8*)&Klds[nt*16 + (l&15)][32 + (l>>4)*8];
      f32x4 acc = {0.f,0.f,0.f,0.f};
      acc = mfma16(a0, b0, acc);
      acc = mfma16(a1, b1, acc);
      #pragma unroll
      for (int r=0; r<4; r++) rsum[r] += __expf(acc[r]*0.125f);
    }
  }
  #pragma unroll
  for (int r=0; r<4; r++){
    float v = rsum[r];
    v += __shfl_xor(v, 1); v += __shfl_xor(v, 2);
    v += __shfl_xor(v, 4); v += __shfl_xor(v, 8);
    rsum[r] = v;
  }
  if ((l & 15) == 0){
    float* dst = rinv + (size_t)(h*NB + b_)*SS + q0 + w*16 + (l>>4)*4;
    #pragma unroll
    for (int r=0; r<4; r++) dst[r] = 1.0f/rsum[r];
  }
}

// ---------------------------------------------------------------------------
// Pass 2 (lite, known-good): recompute scores, write normalized attn (f32).
// ---------------------------------------------------------------------------
__global__ __launch_bounds__(256) void attn_pass2(const unsigned short* __restrict__ qsb,
    const unsigned short* __restrict__ ksb,
    const float* __restrict__ rinv, float* __restrict__ attn){
  const int q0 = blockIdx.x*64, b_ = blockIdx.y, h = blockIdx.z;
  __shared__ alignas(16) unsigned short Qlds[64][72];
  __shared__ alignas(16) unsigned short Klds[64][72];
  const int t = threadIdx.x, w = t>>6, l = t&63;
  const int srow = t>>2, sc0 = (t&3)*16;
  const unsigned short* qsrc = qsb + (((size_t)(h*NB + b_)*SS + q0)<<6);
  const unsigned short* ksrc = ksb + (((size_t)(h*NB + b_)*SS)<<6);
  {
    const ushort8* s0 = (const ushort8*)(qsrc + srow*64 + sc0);
    *(ushort8*)&Qlds[srow][sc0]   = s0[0];
    *(ushort8*)&Qlds[srow][sc0+8] = s0[1];
  }
  float ri[4];
  {
    const float* rp = rinv + (size_t)(h*NB + b_)*SS + q0 + w*16 + (l>>4)*4;
    #pragma unroll
    for (int r=0;r<4;r++) ri[r] = rp[r];
  }
  float* arow = attn + (size_t)(h*NB + b_)*SS*SS + (size_t)q0*SS;
  for (int kt=0; kt<32; kt++){
    ushort8 k0v = *(const ushort8*)(ksrc + ((size_t)(kt*64 + srow)<<6) + sc0);
    ushort8 k1v = *(const ushort8*)(ksrc + ((size_t)(kt*64 + srow)<<6) + sc0 + 8);
    __syncthreads();
    *(ushort8*)&Klds[srow][sc0]   = k0v;
    *(ushort8*)&Klds[srow][sc0+8] = k1v;
    __syncthreads();
    short8 a0 = *(const short8*)&Qlds[w*16 + (l&15)][(l>>4)*8];
    short8 a1 = *(const short8*)&Qlds[w*16 + (l&15)][32 + (l>>4)*8];
    #pragma unroll
    for (int nt=0; nt<4; nt++){
      short8 b0 = *(const short8*)&Klds[nt*16 + (l&15)][(l>>4)*8];
      short8 b1 = *(const short8*)&Klds[nt*16 + (l&15)][32 + (l>>4)*8];
      f32x4 acc = {0.f,0.f,0.f,0.f};
      acc = mfma16(a0, b0, acc);
      acc = mfma16(a1, b1, acc);
      #pragma unroll
      for (int r=0; r<4; r++){
        float p = __expf(acc[r]*0.125f) * ri[r];
        arow[(size_t)(w*16 + (l>>4)*4 + r)*SS + kt*64 + nt*16 + (l&15)] = p;
      }
    }
  }
}

// ---------------------------------------------------------------------------
// PV probe (byte-identical to round 5): P from global attn, V from vst,
// PV via MFMA, head-mean via atomicAdd into macc.
// ---------------------------------------------------------------------------
__global__ __launch_bounds__(256) void pv_mfma(const float* __restrict__ attn,
    const unsigned short* __restrict__ vstb, float* __restrict__ macc){
  const int q0 = blockIdx.x*64, b_ = blockIdx.y, h = blockIdx.z;
  __shared__ alignas(16) unsigned short Plds[64][72];
  __shared__ alignas(16) unsigned short Vlds[64][72];   // [dv][k_local]
  const int t = threadIdx.x, w = t>>6, l = t&63;
  const int srow = t>>2, sc0 = (t&3)*16;
  const float* asrc = attn + (size_t)(h*NB + b_)*SS*SS + (size_t)q0*SS;
  const unsigned short* vsrc = vstb + (size_t)b_*64*2048;
  f32x4 occ[4] = {{0,0,0,0},{0,0,0,0},{0,0,0,0},{0,0,0,0}};
  for (int kt=0; kt<32; kt++){
    const float* prow = asrc + (size_t)srow*SS + kt*64 + sc0;
    f32x4 p0 = *(const f32x4*)prow;
    f32x4 p1 = *(const f32x4*)(prow+4);
    f32x4 p2 = *(const f32x4*)(prow+8);
    f32x4 p3 = *(const f32x4*)(prow+12);
    ushort8 pv0, pv1;
    pv0[0]=f2bf(p0[0]); pv0[1]=f2bf(p0[1]); pv0[2]=f2bf(p0[2]); pv0[3]=f2bf(p0[3]);
    pv0[4]=f2bf(p1[0]); pv0[5]=f2bf(p1[1]); pv0[6]=f2bf(p1[2]); pv0[7]=f2bf(p1[3]);
    pv1[0]=f2bf(p2[0]); pv1[1]=f2bf(p2[1]); pv1[2]=f2bf(p2[2]); pv1[3]=f2bf(p2[3]);
    pv1[4]=f2bf(p3[0]); pv1[5]=f2bf(p3[1]); pv1[6]=f2bf(p3[2]); pv1[7]=f2bf(p3[3]);
    ushort8 v0v = *(const ushort8*)(vsrc + (size_t)srow*2048 + kt*64 + sc0);
    ushort8 v1v = *(const ushort8*)(vsrc + (size_t)srow*2048 + kt*64 + sc0 + 8);
    __syncthreads();
    *(ushort8*)&Plds[srow][sc0]   = pv0;  *(ushort8*)&Plds[srow][sc0+8] = pv1;
    *(ushort8*)&Vlds[srow][sc0]   = v0v;  *(ushort8*)&Vlds[srow][sc0+8] = v1v;
    __syncthreads();
    #pragma unroll
    for (int kk=0; kk<2; kk++){
      short8 pa = *(const short8*)&Plds[w*16 + (l&15)][kk*32 + (l>>4)*8];
      #pragma unroll
      for (int n2=0; n2<4; n2++){
        short8 vb = *(const short8*)&Vlds[n2*16 + (l&15)][kk*32 + (l>>4)*8];
        occ[n2] = mfma16(pa, vb, occ[n2]);
      }
    }
  }
  #pragma unroll
  for (int n2=0; n2<4; n2++){
    #pragma unroll
    for (int r=0; r<4; r++){
      atomicAdd(macc + ((size_t)(b_*SS + q0 + w*16 + (l>>4)*4 + r)<<6) + n2*16 + (l&15),
                occ[n2][r]*0.125f);
    }
  }
}

// ---------------------------------------------------------------------------
// Final: out[b,s,:] = macc[b,s,:] @ Wo[64,512]
// ---------------------------------------------------------------------------
__global__ __launch_bounds__(256) void final_out(const float* __restrict__ macc,
    const float* __restrict__ Wo, float* __restrict__ out){
  __shared__ alignas(16) float mlds[32][68];
  const int t = threadIdx.x;
  const int m0 = blockIdx.x*32;
  {
    int row = t>>3, k0 = (t&7)*8;
    const f32x4* src = (const f32x4*)(macc + (size_t)(m0+row)*64 + k0);
    *(f32x4*)&mlds[row][k0]   = src[0];
    *(f32x4*)&mlds[row][k0+4] = src[1];
  }
  __syncthreads();
  const int mrow = t>>3, n0 = (t&7)*64;
  f32x4 zero = {0.f,0.f,0.f,0.f};
  f32x4 a4[16];
  #pragma unroll
  for (int j=0;j<16;j++) a4[j] = zero;
  for (int k=0; k<64; k++){
    float am = mlds[mrow][k];
    const f32x4* wo4 = (const f32x4*)(Wo + (size_t)k*512 + n0);
    #pragma unroll
    for (int j=0; j<16; j++) a4[j] += am * wo4[j];
  }
  float* dst = out + (size_t)(m0+mrow)*512 + n0;
  #pragma unroll
  for (int j=0; j<16; j++) *(f32x4*)(dst + j*4) = a4[j];
}

// ---------------------------------------------------------------------------
// Scratch plan:
//   d_out head  [0 .. 16.8MB)        : qs_buf | ks_buf  (dead before final_out)
//   attn tail   [last 1MB of attn)   : wq_t | wk_t      (dead before pass2)
//   attn tail-3MB .. tail-1MB        : vs (f32, 2MB)    (dead before pass2)
//   d_ws 3.47MB: rinv 256K | vst 1M | wv_t 64K | macc 2M
// ---------------------------------------------------------------------------
extern "C" void kernel_launch(void* const* d_in, const int* in_sizes, int n_in,
                              void* d_out, int out_size, void* d_ws, size_t ws_size,
                              hipStream_t stream){
  (void)in_sizes; (void)n_in; (void)out_size; (void)ws_size;
  const float* q  = (const float*)d_in[0];
  const float* k  = (const float*)d_in[1];
  const float* v  = (const float*)d_in[2];
  const float* Wq = (const float*)d_in[3];
  const float* Wk = (const float*)d_in[4];
  const float* Wv = (const float*)d_in[5];
  const float* Wo = (const float*)d_in[6];
  float* out  = (float*)d_out;
  float* attn = out + (size_t)NB*SS*DMODEL;   // outputs concatenated: out, attn

  unsigned short* qs_buf = (unsigned short*)d_out;
  unsigned short* ks_buf = qs_buf + (size_t)NH*NB*SS*DKK;
  unsigned short* w_tail = (unsigned short*)(attn + (size_t)NH*NB*SS*SS) - (262144 + 262144);
  unsigned short* wq_t = w_tail;
  unsigned short* wk_t = w_tail + 262144;
  float* vs = (float*)w_tail - (size_t)NB*SS*DKK;  // 2MB f32 just below weight tail

  float* rinv          = (float*)d_ws;                              // 262,144 B
  unsigned short* vst  = (unsigned short*)((char*)d_ws + 262144);   // 1,048,576 B
  unsigned short* wv_t = (unsigned short*)((char*)d_ws + 1310720);  //    65,536 B (unused)
  float* macc          = (float*)((char*)d_ws + 1376256);           // 2,097,152 B

  prep_w<<<dim3(1152), 256, 0, stream>>>(Wq, Wk, Wv, wq_t, wk_t, wv_t);
  zero_macc<<<dim3(512), 256, 0, stream>>>(macc);
  proj_qk<<<dim3(128, 8), 256, 0, stream>>>(q, wq_t, qs_buf);
  proj_qk<<<dim3(128, 8), 256, 0, stream>>>(k, wk_t, ks_buf);
  vs_f32<<<dim3(2048), 256, 0, stream>>>(v, Wv, vs);
  transpose_v<<<dim3(2048), 256, 0, stream>>>(vs, vst);
  attn_pass1<<<dim3(32, NB, NH), 256, 0, stream>>>(qs_buf, ks_buf, rinv);
  attn_pass2<<<dim3(32, NB, NH), 256, 0, stream>>>(qs_buf, ks_buf, rinv, attn);
  pv_mfma<<<dim3(32, NB, NH), 256, 0, stream>>>(attn, vst, macc);
  final_out<<<dim3(256), 256, 0, stream>>>(macc, Wo, out);
}

// Round 7
// 440.471 us; speedup vs baseline: 1.5471x; 1.3641x over previous
//
#include <hip/hip_runtime.h>
#include <hip/hip_bf16.h>
#include <cstdint>
#include <cstddef>

#define NB 4
#define SS 2048
#define DMODEL 512
#define NH 8
#define DKK 64

typedef __attribute__((ext_vector_type(8))) short short8;
typedef __attribute__((ext_vector_type(8))) unsigned short ushort8;
typedef __attribute__((ext_vector_type(4))) float f32x4;

static __device__ __forceinline__ unsigned short f2bf(float f){
  unsigned int u = __float_as_uint(f);
  u += 0x7fff + ((u >> 16) & 1);   // round-to-nearest-even
  return (unsigned short)(u >> 16);
}

static __device__ __forceinline__ f32x4 mfma16(short8 a, short8 b, f32x4 c){
  return __builtin_amdgcn_mfma_f32_16x16x32_bf16(a, b, c, 0, 0, 0);
}

// ---------------------------------------------------------------------------
// Weight prep: wq_t/wk_t[col][d] bf16 (col = h*64+n).
// ---------------------------------------------------------------------------
__global__ __launch_bounds__(256) void prep_w(const float* __restrict__ Wq,
    const float* __restrict__ Wk,
    unsigned short* __restrict__ wq_t, unsigned short* __restrict__ wk_t){
  int i = blockIdx.x*256 + threadIdx.x;
  if (i < 512*512){
    int col = i >> 9, d = i & 511;
    int src = (col >> 6)*(512*64) + d*64 + (col & 63);
    wq_t[i] = f2bf(Wq[src]);
    wk_t[i] = f2bf(Wk[src]);
  }
}

// ---------------------------------------------------------------------------
// zero macc: 512 blocks x 256 threads x 4 floats = 524,288 floats (exact).
// ---------------------------------------------------------------------------
__global__ __launch_bounds__(256) void zero_macc(float* __restrict__ macc){
  f32x4 z = {0.f,0.f,0.f,0.f};
  *(f32x4*)(macc + ((size_t)blockIdx.x*256 + threadIdx.x)*4) = z;
}

// ---------------------------------------------------------------------------
// Projection GEMM for Q/K: out[h][b][s][n] = bf16( A[b,s,:] @ W[h,:,n] )
// (validated R3/R6)
// ---------------------------------------------------------------------------
__global__ __launch_bounds__(256) void proj_qk(const float* __restrict__ A,
    const unsigned short* __restrict__ Wt, unsigned short* __restrict__ outb){
  const int m0 = blockIdx.x*64;
  const int h  = blockIdx.y;
  __shared__ alignas(16) unsigned short Alds[64][40];
  __shared__ alignas(16) unsigned short Wlds[64][40];
  const int t = threadIdx.x, w = t>>6, l = t&63;
  const int srow = t>>2, sk0 = (t&3)*8;
  f32x4 acc[4] = {{0,0,0,0},{0,0,0,0},{0,0,0,0},{0,0,0,0}};
  for (int ks=0; ks<512; ks+=32){
    const float* asrc = A + (size_t)(m0+srow)*512 + ks + sk0;
    f32x4 f0 = *(const f32x4*)asrc;
    f32x4 f1 = *(const f32x4*)(asrc+4);
    ushort8 av;
    av[0]=f2bf(f0[0]); av[1]=f2bf(f0[1]); av[2]=f2bf(f0[2]); av[3]=f2bf(f0[3]);
    av[4]=f2bf(f1[0]); av[5]=f2bf(f1[1]); av[6]=f2bf(f1[2]); av[7]=f2bf(f1[3]);
    ushort8 wv8 = *(const ushort8*)(Wt + (size_t)(h*64+srow)*512 + ks + sk0);
    __syncthreads();
    *(ushort8*)&Alds[srow][sk0] = av;
    *(ushort8*)&Wlds[srow][sk0] = wv8;
    __syncthreads();
    short8 a = *(const short8*)&Alds[w*16 + (l&15)][(l>>4)*8];
    #pragma unroll
    for (int nt=0; nt<4; nt++){
      short8 b = *(const short8*)&Wlds[nt*16 + (l&15)][(l>>4)*8];
      acc[nt] = mfma16(a, b, acc[nt]);
    }
  }
  #pragma unroll
  for (int nt=0; nt<4; nt++){
    #pragma unroll
    for (int r=0; r<4; r++){
      int m = m0 + w*16 + (l>>4)*4 + r;
      int b_ = m >> 11, s_ = m & 2047;
      outb[(((size_t)(h*NB + b_)*SS + s_)<<6) + nt*16 + (l&15)] = f2bf(acc[nt][r]);
    }
  }
}

// ---------------------------------------------------------------------------
// vs[b][s][dv] = v[b,s,:] @ Wv  (validated R3/R6; pure f32 VALU)
// ---------------------------------------------------------------------------
__global__ __launch_bounds__(256) void vs_f32(const float* __restrict__ v,
    const float* __restrict__ Wv, float* __restrict__ vs){
  __shared__ float vrow[4][512];
  const int t = threadIdx.x;
  const int M = blockIdx.x*4;   // global row in [0,8192)
  for (int i = t; i < 4*512; i += 256)
    vrow[i>>9][i&511] = v[(size_t)(M + (i>>9))*512 + (i&511)];
  __syncthreads();
  const int r = t>>6, dv = t&63;
  float acc = 0.f;
  for (int d = 0; d < 512; d++)
    acc += vrow[r][d] * Wv[d*64 + dv];
  vs[(size_t)(M + r)*64 + dv] = acc;
}

// ---------------------------------------------------------------------------
// Trivially-correct transpose (validated R6): vst[b][dv][s] = bf16(vs[b][s][dv]).
// ---------------------------------------------------------------------------
__global__ __launch_bounds__(256) void transpose_v(const float* __restrict__ vs,
    unsigned short* __restrict__ vst){
  int idx = blockIdx.x*256 + threadIdx.x;      // 0 .. 524287
  int dv = idx & 63;
  int sg = idx >> 6;                           // global s-row 0..8191
  int b_ = sg >> 11, s_ = sg & 2047;
  vst[((size_t)(b_*64 + dv))*2048 + s_] = f2bf(vs[idx]);
}

// ---------------------------------------------------------------------------
// Pass 1 (validated): per-row sum of exp(score*scale) -> rinv = 1/sum.
// ---------------------------------------------------------------------------
__global__ __launch_bounds__(256) void attn_pass1(const unsigned short* __restrict__ qsb,
    const unsigned short* __restrict__ ksb, float* __restrict__ rinv){
  const int q0 = blockIdx.x*64, b_ = blockIdx.y, h = blockIdx.z;
  __shared__ alignas(16) unsigned short Qlds[64][72];
  __shared__ alignas(16) unsigned short Klds[64][72];
  const int t = threadIdx.x, w = t>>6, l = t&63;
  const int srow = t>>2, sc0 = (t&3)*16;
  const unsigned short* qsrc = qsb + (((size_t)(h*NB + b_)*SS + q0)<<6);
  const unsigned short* ksrc = ksb + (((size_t)(h*NB + b_)*SS)<<6);
  {
    const ushort8* s0 = (const ushort8*)(qsrc + srow*64 + sc0);
    *(ushort8*)&Qlds[srow][sc0]   = s0[0];
    *(ushort8*)&Qlds[srow][sc0+8] = s0[1];
  }
  float rsum[4] = {0.f,0.f,0.f,0.f};
  for (int kt=0; kt<32; kt++){
    ushort8 k0v = *(const ushort8*)(ksrc + ((size_t)(kt*64 + srow)<<6) + sc0);
    ushort8 k1v = *(const ushort8*)(ksrc + ((size_t)(kt*64 + srow)<<6) + sc0 + 8);
    __syncthreads();
    *(ushort8*)&Klds[srow][sc0]   = k0v;
    *(ushort8*)&Klds[srow][sc0+8] = k1v;
    __syncthreads();
    short8 a0 = *(const short8*)&Qlds[w*16 + (l&15)][(l>>4)*8];
    short8 a1 = *(const short8*)&Qlds[w*16 + (l&15)][32 + (l>>4)*8];
    #pragma unroll
    for (int nt=0; nt<4; nt++){
      short8 b0 = *(const short8*)&Klds[nt*16 + (l&15)][(l>>4)*8];
      short8 b1 = *(const short8*)&Klds[nt*16 + (l&15)][32 + (l>>4)*8];
      f32x4 acc = {0.f,0.f,0.f,0.f};
      acc = mfma16(a0, b0, acc);
      acc = mfma16(a1, b1, acc);
      #pragma unroll
      for (int r=0; r<4; r++) rsum[r] += __expf(acc[r]*0.125f);
    }
  }
  #pragma unroll
  for (int r=0; r<4; r++){
    float v = rsum[r];
    v += __shfl_xor(v, 1); v += __shfl_xor(v, 2);
    v += __shfl_xor(v, 4); v += __shfl_xor(v, 8);
    rsum[r] = v;
  }
  if ((l & 15) == 0){
    float* dst = rinv + (size_t)(h*NB + b_)*SS + q0 + w*16 + (l>>4)*4;
    #pragma unroll
    for (int r=0; r<4; r++) dst[r] = 1.0f/rsum[r];
  }
}

// ---------------------------------------------------------------------------
// Pass 2 (fused): recompute scores, write normalized attn (f32), PV via MFMA
// (P roundtrip through per-wave LDS; read pattern == validated pv_mfma),
// head-mean via atomicAdd into macc.
// ---------------------------------------------------------------------------
__global__ __launch_bounds__(256) void attn_pass2(const unsigned short* __restrict__ qsb,
    const unsigned short* __restrict__ ksb, const unsigned short* __restrict__ vstb,
    const float* __restrict__ rinv, float* __restrict__ attn, float* __restrict__ macc){
  const int q0 = blockIdx.x*64, b_ = blockIdx.y, h = blockIdx.z;
  __shared__ alignas(16) unsigned short Qlds[64][72];
  __shared__ alignas(16) unsigned short Klds[64][72];
  __shared__ alignas(16) unsigned short Vlds[64][72];   // [dv][k_local]
  __shared__ alignas(16) unsigned short Plds[4][16][72];
  const int t = threadIdx.x, w = t>>6, l = t&63;
  const int srow = t>>2, sc0 = (t&3)*16;
  const unsigned short* qsrc = qsb + (((size_t)(h*NB + b_)*SS + q0)<<6);
  const unsigned short* ksrc = ksb + (((size_t)(h*NB + b_)*SS)<<6);
  const unsigned short* vsrc = vstb + (size_t)b_*64*2048;
  {
    const ushort8* s0 = (const ushort8*)(qsrc + srow*64 + sc0);
    *(ushort8*)&Qlds[srow][sc0]   = s0[0];
    *(ushort8*)&Qlds[srow][sc0+8] = s0[1];
  }
  float ri[4];
  {
    const float* rp = rinv + (size_t)(h*NB + b_)*SS + q0 + w*16 + (l>>4)*4;
    #pragma unroll
    for (int r=0;r<4;r++) ri[r] = rp[r];
  }
  f32x4 occ[4] = {{0,0,0,0},{0,0,0,0},{0,0,0,0},{0,0,0,0}};
  float* arow = attn + (size_t)(h*NB + b_)*SS*SS + (size_t)q0*SS;
  for (int kt=0; kt<32; kt++){
    ushort8 k0v = *(const ushort8*)(ksrc + ((size_t)(kt*64 + srow)<<6) + sc0);
    ushort8 k1v = *(const ushort8*)(ksrc + ((size_t)(kt*64 + srow)<<6) + sc0 + 8);
    ushort8 v0v = *(const ushort8*)(vsrc + (size_t)srow*2048 + kt*64 + sc0);
    ushort8 v1v = *(const ushort8*)(vsrc + (size_t)srow*2048 + kt*64 + sc0 + 8);
    __syncthreads();
    *(ushort8*)&Klds[srow][sc0]   = k0v;  *(ushort8*)&Klds[srow][sc0+8] = k1v;
    *(ushort8*)&Vlds[srow][sc0]   = v0v;  *(ushort8*)&Vlds[srow][sc0+8] = v1v;
    __syncthreads();
    short8 a0 = *(const short8*)&Qlds[w*16 + (l&15)][(l>>4)*8];
    short8 a1 = *(const short8*)&Qlds[w*16 + (l&15)][32 + (l>>4)*8];
    #pragma unroll
    for (int nt=0; nt<4; nt++){
      short8 b0 = *(const short8*)&Klds[nt*16 + (l&15)][(l>>4)*8];
      short8 b1 = *(const short8*)&Klds[nt*16 + (l&15)][32 + (l>>4)*8];
      f32x4 acc = {0.f,0.f,0.f,0.f};
      acc = mfma16(a0, b0, acc);
      acc = mfma16(a1, b1, acc);
      #pragma unroll
      for (int r=0; r<4; r++){
        float p = __expf(acc[r]*0.125f) * ri[r];
        arow[(size_t)(w*16 + (l>>4)*4 + r)*SS + kt*64 + nt*16 + (l&15)] = p;
        Plds[w][(l>>4)*4 + r][nt*16 + (l&15)] = f2bf(p);
      }
    }
    __syncthreads();   // order P writes vs cross-lane P reads
    #pragma unroll
    for (int kk=0; kk<2; kk++){
      short8 pa = *(const short8*)&Plds[w][l&15][kk*32 + (l>>4)*8];
      #pragma unroll
      for (int n2=0; n2<4; n2++){
        short8 vb = *(const short8*)&Vlds[n2*16 + (l&15)][kk*32 + (l>>4)*8];
        occ[n2] = mfma16(pa, vb, occ[n2]);
      }
    }
  }
  #pragma unroll
  for (int n2=0; n2<4; n2++){
    #pragma unroll
    for (int r=0; r<4; r++){
      atomicAdd(macc + ((size_t)(b_*SS + q0 + w*16 + (l>>4)*4 + r)<<6) + n2*16 + (l&15),
                occ[n2][r]*0.125f);
    }
  }
}

// ---------------------------------------------------------------------------
// Final: out[b,s,:] = macc[b,s,:] @ Wo[64,512]  (validated)
// ---------------------------------------------------------------------------
__global__ __launch_bounds__(256) void final_out(const float* __restrict__ macc,
    const float* __restrict__ Wo, float* __restrict__ out){
  __shared__ alignas(16) float mlds[32][68];
  const int t = threadIdx.x;
  const int m0 = blockIdx.x*32;
  {
    int row = t>>3, k0 = (t&7)*8;
    const f32x4* src = (const f32x4*)(macc + (size_t)(m0+row)*64 + k0);
    *(f32x4*)&mlds[row][k0]   = src[0];
    *(f32x4*)&mlds[row][k0+4] = src[1];
  }
  __syncthreads();
  const int mrow = t>>3, n0 = (t&7)*64;
  f32x4 zero = {0.f,0.f,0.f,0.f};
  f32x4 a4[16];
  #pragma unroll
  for (int j=0;j<16;j++) a4[j] = zero;
  for (int k=0; k<64; k++){
    float am = mlds[mrow][k];
    const f32x4* wo4 = (const f32x4*)(Wo + (size_t)k*512 + n0);
    #pragma unroll
    for (int j=0; j<16; j++) a4[j] += am * wo4[j];
  }
  float* dst = out + (size_t)(m0+mrow)*512 + n0;
  #pragma unroll
  for (int j=0; j<16; j++) *(f32x4*)(dst + j*4) = a4[j];
}

// ---------------------------------------------------------------------------
// Scratch plan:
//   d_out head  [0 .. 16.8MB)        : qs_buf | ks_buf  (dead before final_out)
//   attn tail   [last 1MB of attn)   : wq_t | wk_t      (dead before pass2)
//   attn tail-3MB .. tail-1MB        : vs (f32, 2MB)    (dead before pass2)
//   d_ws 3.41MB: rinv 256K | vst 1M | macc 2M
// ---------------------------------------------------------------------------
extern "C" void kernel_launch(void* const* d_in, const int* in_sizes, int n_in,
                              void* d_out, int out_size, void* d_ws, size_t ws_size,
                              hipStream_t stream){
  (void)in_sizes; (void)n_in; (void)out_size; (void)ws_size;
  const float* q  = (const float*)d_in[0];
  const float* k  = (const float*)d_in[1];
  const float* v  = (const float*)d_in[2];
  const float* Wq = (const float*)d_in[3];
  const float* Wk = (const float*)d_in[4];
  const float* Wv = (const float*)d_in[5];
  const float* Wo = (const float*)d_in[6];
  float* out  = (float*)d_out;
  float* attn = out + (size_t)NB*SS*DMODEL;   // outputs concatenated: out, attn

  unsigned short* qs_buf = (unsigned short*)d_out;
  unsigned short* ks_buf = qs_buf + (size_t)NH*NB*SS*DKK;
  unsigned short* w_tail = (unsigned short*)(attn + (size_t)NH*NB*SS*SS) - (262144 + 262144);
  unsigned short* wq_t = w_tail;
  unsigned short* wk_t = w_tail + 262144;
  float* vs = (float*)w_tail - (size_t)NB*SS*DKK;  // 2MB f32 just below weight tail

  float* rinv          = (float*)d_ws;                              // 262,144 B
  unsigned short* vst  = (unsigned short*)((char*)d_ws + 262144);   // 1,048,576 B
  float* macc          = (float*)((char*)d_ws + 1310720);           // 2,097,152 B

  prep_w<<<dim3(1024), 256, 0, stream>>>(Wq, Wk, wq_t, wk_t);
  zero_macc<<<dim3(512), 256, 0, stream>>>(macc);
  proj_qk<<<dim3(128, 8), 256, 0, stream>>>(q, wq_t, qs_buf);
  proj_qk<<<dim3(128, 8), 256, 0, stream>>>(k, wk_t, ks_buf);
  vs_f32<<<dim3(2048), 256, 0, stream>>>(v, Wv, vs);
  transpose_v<<<dim3(2048), 256, 0, stream>>>(vs, vst);
  attn_pass1<<<dim3(32, NB, NH), 256, 0, stream>>>(qs_buf, ks_buf, rinv);
  attn_pass2<<<dim3(32, NB, NH), 256, 0, stream>>>(qs_buf, ks_buf, vst, rinv, attn, macc);
  final_out<<<dim3(256), 256, 0, stream>>>(macc, Wo, out);
}

// Round 8
// 417.598 us; speedup vs baseline: 1.6319x; 1.0548x over previous
//
#include <hip/hip_runtime.h>
#include <hip/hip_bf16.h>
#include <cstdint>
#include <cstddef>

#define NB 4
#define SS 2048
#define DMODEL 512
#define NH 8
#define DKK 64

typedef __attribute__((ext_vector_type(8))) short short8;
typedef __attribute__((ext_vector_type(8))) unsigned short ushort8;
typedef __attribute__((ext_vector_type(4))) float f32x4;

static __device__ __forceinline__ unsigned short f2bf(float f){
  unsigned int u = __float_as_uint(f);
  u += 0x7fff + ((u >> 16) & 1);   // round-to-nearest-even
  return (unsigned short)(u >> 16);
}

static __device__ __forceinline__ f32x4 mfma16(short8 a, short8 b, f32x4 c){
  return __builtin_amdgcn_mfma_f32_16x16x32_bf16(a, b, c, 0, 0, 0);
}

// ---------------------------------------------------------------------------
// Weight prep: wq_t/wk_t[col][d] bf16 (col = h*64+n).
// ---------------------------------------------------------------------------
__global__ __launch_bounds__(256) void prep_w(const float* __restrict__ Wq,
    const float* __restrict__ Wk,
    unsigned short* __restrict__ wq_t, unsigned short* __restrict__ wk_t){
  int i = blockIdx.x*256 + threadIdx.x;
  if (i < 512*512){
    int col = i >> 9, d = i & 511;
    int src = (col >> 6)*(512*64) + d*64 + (col & 63);
    wq_t[i] = f2bf(Wq[src]);
    wk_t[i] = f2bf(Wk[src]);
  }
}

// ---------------------------------------------------------------------------
// zero macc: 512 blocks x 256 threads x 4 floats = 524,288 floats (exact).
// ---------------------------------------------------------------------------
__global__ __launch_bounds__(256) void zero_macc(float* __restrict__ macc){
  f32x4 z = {0.f,0.f,0.f,0.f};
  *(f32x4*)(macc + ((size_t)blockIdx.x*256 + threadIdx.x)*4) = z;
}

// ---------------------------------------------------------------------------
// Projection GEMM for Q/K: out[h][b][s][n] = bf16( A[b,s,:] @ W[h,:,n] )
// (validated R3/R6)
// ---------------------------------------------------------------------------
__global__ __launch_bounds__(256) void proj_qk(const float* __restrict__ A,
    const unsigned short* __restrict__ Wt, unsigned short* __restrict__ outb){
  const int m0 = blockIdx.x*64;
  const int h  = blockIdx.y;
  __shared__ alignas(16) unsigned short Alds[64][40];
  __shared__ alignas(16) unsigned short Wlds[64][40];
  const int t = threadIdx.x, w = t>>6, l = t&63;
  const int srow = t>>2, sk0 = (t&3)*8;
  f32x4 acc[4] = {{0,0,0,0},{0,0,0,0},{0,0,0,0},{0,0,0,0}};
  for (int ks=0; ks<512; ks+=32){
    const float* asrc = A + (size_t)(m0+srow)*512 + ks + sk0;
    f32x4 f0 = *(const f32x4*)asrc;
    f32x4 f1 = *(const f32x4*)(asrc+4);
    ushort8 av;
    av[0]=f2bf(f0[0]); av[1]=f2bf(f0[1]); av[2]=f2bf(f0[2]); av[3]=f2bf(f0[3]);
    av[4]=f2bf(f1[0]); av[5]=f2bf(f1[1]); av[6]=f2bf(f1[2]); av[7]=f2bf(f1[3]);
    ushort8 wv8 = *(const ushort8*)(Wt + (size_t)(h*64+srow)*512 + ks + sk0);
    __syncthreads();
    *(ushort8*)&Alds[srow][sk0] = av;
    *(ushort8*)&Wlds[srow][sk0] = wv8;
    __syncthreads();
    short8 a = *(const short8*)&Alds[w*16 + (l&15)][(l>>4)*8];
    #pragma unroll
    for (int nt=0; nt<4; nt++){
      short8 b = *(const short8*)&Wlds[nt*16 + (l&15)][(l>>4)*8];
      acc[nt] = mfma16(a, b, acc[nt]);
    }
  }
  #pragma unroll
  for (int nt=0; nt<4; nt++){
    #pragma unroll
    for (int r=0; r<4; r++){
      int m = m0 + w*16 + (l>>4)*4 + r;
      int b_ = m >> 11, s_ = m & 2047;
      outb[(((size_t)(h*NB + b_)*SS + s_)<<6) + nt*16 + (l&15)] = f2bf(acc[nt][r]);
    }
  }
}

// ---------------------------------------------------------------------------
// vs[b][s][dv] = v[b,s,:] @ Wv  (validated R3/R6; pure f32 VALU)
// ---------------------------------------------------------------------------
__global__ __launch_bounds__(256) void vs_f32(const float* __restrict__ v,
    const float* __restrict__ Wv, float* __restrict__ vs){
  __shared__ float vrow[4][512];
  const int t = threadIdx.x;
  const int M = blockIdx.x*4;   // global row in [0,8192)
  for (int i = t; i < 4*512; i += 256)
    vrow[i>>9][i&511] = v[(size_t)(M + (i>>9))*512 + (i&511)];
  __syncthreads();
  const int r = t>>6, dv = t&63;
  float acc = 0.f;
  for (int d = 0; d < 512; d++)
    acc += vrow[r][d] * Wv[d*64 + dv];
  vs[(size_t)(M + r)*64 + dv] = acc;
}

// ---------------------------------------------------------------------------
// Trivially-correct transpose (validated R6): vst[b][dv][s] = bf16(vs[b][s][dv]).
// ---------------------------------------------------------------------------
__global__ __launch_bounds__(256) void transpose_v(const float* __restrict__ vs,
    unsigned short* __restrict__ vst){
  int idx = blockIdx.x*256 + threadIdx.x;      // 0 .. 524287
  int dv = idx & 63;
  int sg = idx >> 6;                           // global s-row 0..8191
  int b_ = sg >> 11, s_ = sg & 2047;
  vst[((size_t)(b_*64 + dv))*2048 + s_] = f2bf(vs[idx]);
}

// ---------------------------------------------------------------------------
// Fused attention: loop1 computes rsum (in-register ri via butterfly reduce),
// loop2 recomputes scores, writes normalized attn, PV via MFMA (per-wave Plds
// roundtrip ordered by lgkmcnt(0)+sched_barrier, not a block barrier),
// head-mean via atomicAdd into macc.  Fragment mappings byte-identical to
// the R6/R7-validated kernels; Q frags hoisted to registers (direct global).
// ---------------------------------------------------------------------------
__global__ __launch_bounds__(256) void attn_fused(const unsigned short* __restrict__ qsb,
    const unsigned short* __restrict__ ksb, const unsigned short* __restrict__ vstb,
    float* __restrict__ attn, float* __restrict__ macc){
  const int q0 = blockIdx.x*64, b_ = blockIdx.y, h = blockIdx.z;
  __shared__ alignas(16) unsigned short Klds[64][72];
  __shared__ alignas(16) unsigned short Vlds[64][72];   // [dv][k_local]
  __shared__ alignas(16) unsigned short Plds[4][16][72];
  const int t = threadIdx.x, w = t>>6, l = t&63;
  const int srow = t>>2, sc0 = (t&3)*16;
  const unsigned short* qsrc = qsb + (((size_t)(h*NB + b_)*SS + q0)<<6);
  const unsigned short* ksrc = ksb + (((size_t)(h*NB + b_)*SS)<<6);
  const unsigned short* vsrc = vstb + (size_t)b_*64*2048;

  // Q fragments: row = w*16 + (l&15), cols (l>>4)*8 .. +7 and +32 (16B aligned)
  short8 a0 = *(const short8*)(qsrc + (size_t)(w*16 + (l&15))*64 + (l>>4)*8);
  short8 a1 = *(const short8*)(qsrc + (size_t)(w*16 + (l&15))*64 + 32 + (l>>4)*8);

  // ---- loop 1: row sums of exp(score*scale) ----
  float rsum[4] = {0.f,0.f,0.f,0.f};
  for (int kt=0; kt<32; kt++){
    ushort8 k0v = *(const ushort8*)(ksrc + ((size_t)(kt*64 + srow)<<6) + sc0);
    ushort8 k1v = *(const ushort8*)(ksrc + ((size_t)(kt*64 + srow)<<6) + sc0 + 8);
    __syncthreads();
    *(ushort8*)&Klds[srow][sc0]   = k0v;
    *(ushort8*)&Klds[srow][sc0+8] = k1v;
    __syncthreads();
    #pragma unroll
    for (int nt=0; nt<4; nt++){
      short8 b0 = *(const short8*)&Klds[nt*16 + (l&15)][(l>>4)*8];
      short8 b1 = *(const short8*)&Klds[nt*16 + (l&15)][32 + (l>>4)*8];
      f32x4 acc = {0.f,0.f,0.f,0.f};
      acc = mfma16(a0, b0, acc);
      acc = mfma16(a1, b1, acc);
      #pragma unroll
      for (int r=0; r<4; r++) rsum[r] += __expf(acc[r]*0.125f);
    }
  }
  float ri[4];
  #pragma unroll
  for (int r=0; r<4; r++){
    float v = rsum[r];
    v += __shfl_xor(v, 1); v += __shfl_xor(v, 2);
    v += __shfl_xor(v, 4); v += __shfl_xor(v, 8);
    ri[r] = 1.0f / v;     // butterfly leaves total in ALL lanes
  }

  // ---- loop 2: normalized attn writes + PV accumulate ----
  f32x4 occ[4] = {{0,0,0,0},{0,0,0,0},{0,0,0,0},{0,0,0,0}};
  float* arow = attn + (size_t)(h*NB + b_)*SS*SS + (size_t)q0*SS;
  for (int kt=0; kt<32; kt++){
    ushort8 k0v = *(const ushort8*)(ksrc + ((size_t)(kt*64 + srow)<<6) + sc0);
    ushort8 k1v = *(const ushort8*)(ksrc + ((size_t)(kt*64 + srow)<<6) + sc0 + 8);
    ushort8 v0v = *(const ushort8*)(vsrc + (size_t)srow*2048 + kt*64 + sc0);
    ushort8 v1v = *(const ushort8*)(vsrc + (size_t)srow*2048 + kt*64 + sc0 + 8);
    __syncthreads();   // prev iteration's Klds/Vlds reads complete
    *(ushort8*)&Klds[srow][sc0]   = k0v;  *(ushort8*)&Klds[srow][sc0+8] = k1v;
    *(ushort8*)&Vlds[srow][sc0]   = v0v;  *(ushort8*)&Vlds[srow][sc0+8] = v1v;
    __syncthreads();   // tiles staged
    #pragma unroll
    for (int nt=0; nt<4; nt++){
      short8 b0 = *(const short8*)&Klds[nt*16 + (l&15)][(l>>4)*8];
      short8 b1 = *(const short8*)&Klds[nt*16 + (l&15)][32 + (l>>4)*8];
      f32x4 acc = {0.f,0.f,0.f,0.f};
      acc = mfma16(a0, b0, acc);
      acc = mfma16(a1, b1, acc);
      #pragma unroll
      for (int r=0; r<4; r++){
        float p = __expf(acc[r]*0.125f) * ri[r];
        arow[(size_t)(w*16 + (l>>4)*4 + r)*SS + kt*64 + nt*16 + (l&15)] = p;
        Plds[w][(l>>4)*4 + r][nt*16 + (l&15)] = f2bf(p);
      }
    }
    // Plds is wave-private: order its writes vs the cross-lane reads with a
    // per-wave LDS drain (no block barrier needed).  rule-#18 fence pattern.
    asm volatile("s_waitcnt lgkmcnt(0)" ::: "memory");
    __builtin_amdgcn_sched_barrier(0);
    #pragma unroll
    for (int kk=0; kk<2; kk++){
      short8 pa = *(const short8*)&Plds[w][l&15][kk*32 + (l>>4)*8];
      #pragma unroll
      for (int n2=0; n2<4; n2++){
        short8 vb = *(const short8*)&Vlds[n2*16 + (l&15)][kk*32 + (l>>4)*8];
        occ[n2] = mfma16(pa, vb, occ[n2]);
      }
    }
  }
  #pragma unroll
  for (int n2=0; n2<4; n2++){
    #pragma unroll
    for (int r=0; r<4; r++){
      atomicAdd(macc + ((size_t)(b_*SS + q0 + w*16 + (l>>4)*4 + r)<<6) + n2*16 + (l&15),
                occ[n2][r]*0.125f);
    }
  }
}

// ---------------------------------------------------------------------------
// Final: out[b,s,:] = macc[b,s,:] @ Wo[64,512]  (validated)
// ---------------------------------------------------------------------------
__global__ __launch_bounds__(256) void final_out(const float* __restrict__ macc,
    const float* __restrict__ Wo, float* __restrict__ out){
  __shared__ alignas(16) float mlds[32][68];
  const int t = threadIdx.x;
  const int m0 = blockIdx.x*32;
  {
    int row = t>>3, k0 = (t&7)*8;
    const f32x4* src = (const f32x4*)(macc + (size_t)(m0+row)*64 + k0);
    *(f32x4*)&mlds[row][k0]   = src[0];
    *(f32x4*)&mlds[row][k0+4] = src[1];
  }
  __syncthreads();
  const int mrow = t>>3, n0 = (t&7)*64;
  f32x4 zero = {0.f,0.f,0.f,0.f};
  f32x4 a4[16];
  #pragma unroll
  for (int j=0;j<16;j++) a4[j] = zero;
  for (int k=0; k<64; k++){
    float am = mlds[mrow][k];
    const f32x4* wo4 = (const f32x4*)(Wo + (size_t)k*512 + n0);
    #pragma unroll
    for (int j=0; j<16; j++) a4[j] += am * wo4[j];
  }
  float* dst = out + (size_t)(m0+mrow)*512 + n0;
  #pragma unroll
  for (int j=0; j<16; j++) *(f32x4*)(dst + j*4) = a4[j];
}

// ---------------------------------------------------------------------------
// Scratch plan:
//   d_out head  [0 .. 16.8MB)        : qs_buf | ks_buf  (dead before final_out)
//   attn tail   [last 1MB of attn)   : wq_t | wk_t      (dead before attn_fused)
//   attn tail-3MB .. tail-1MB        : vs (f32, 2MB)    (dead before attn_fused)
//   d_ws 3.41MB: (256K unused) | vst 1M | macc 2M
// ---------------------------------------------------------------------------
extern "C" void kernel_launch(void* const* d_in, const int* in_sizes, int n_in,
                              void* d_out, int out_size, void* d_ws, size_t ws_size,
                              hipStream_t stream){
  (void)in_sizes; (void)n_in; (void)out_size; (void)ws_size;
  const float* q  = (const float*)d_in[0];
  const float* k  = (const float*)d_in[1];
  const float* v  = (const float*)d_in[2];
  const float* Wq = (const float*)d_in[3];
  const float* Wk = (const float*)d_in[4];
  const float* Wv = (const float*)d_in[5];
  const float* Wo = (const float*)d_in[6];
  float* out  = (float*)d_out;
  float* attn = out + (size_t)NB*SS*DMODEL;   // outputs concatenated: out, attn

  unsigned short* qs_buf = (unsigned short*)d_out;
  unsigned short* ks_buf = qs_buf + (size_t)NH*NB*SS*DKK;
  unsigned short* w_tail = (unsigned short*)(attn + (size_t)NH*NB*SS*SS) - (262144 + 262144);
  unsigned short* wq_t = w_tail;
  unsigned short* wk_t = w_tail + 262144;
  float* vs = (float*)w_tail - (size_t)NB*SS*DKK;  // 2MB f32 just below weight tail

  unsigned short* vst  = (unsigned short*)((char*)d_ws + 262144);   // 1,048,576 B
  float* macc          = (float*)((char*)d_ws + 1310720);           // 2,097,152 B

  prep_w<<<dim3(1024), 256, 0, stream>>>(Wq, Wk, wq_t, wk_t);
  zero_macc<<<dim3(512), 256, 0, stream>>>(macc);
  proj_qk<<<dim3(128, 8), 256, 0, stream>>>(q, wq_t, qs_buf);
  proj_qk<<<dim3(128, 8), 256, 0, stream>>>(k, wk_t, ks_buf);
  vs_f32<<<dim3(2048), 256, 0, stream>>>(v, Wv, vs);
  transpose_v<<<dim3(2048), 256, 0, stream>>>(vs, vst);
  attn_fused<<<dim3(32, NB, NH), 256, 0, stream>>>(qs_buf, ks_buf, vst, attn, macc);
  final_out<<<dim3(256), 256, 0, stream>>>(macc, Wo, out);
}

// Round 10
// 415.282 us; speedup vs baseline: 1.6410x; 1.0056x over previous
//
#include <hip/hip_runtime.h>
#include <hip/hip_bf16.h>
#include <cstdint>
#include <cstddef>

#define NB 4
#define SS 2048
#define DMODEL 512
#define NH 8
#define DKK 64

typedef __attribute__((ext_vector_type(8))) short short8;
typedef __attribute__((ext_vector_type(4))) short s16x4;
typedef __attribute__((ext_vector_type(8))) unsigned short ushort8;
typedef __attribute__((ext_vector_type(4))) float f32x4;

static __device__ __forceinline__ unsigned short f2bf(float f){
  unsigned int u = __float_as_uint(f);
  u += 0x7fff + ((u >> 16) & 1);   // round-to-nearest-even
  return (unsigned short)(u >> 16);
}

static __device__ __forceinline__ f32x4 mfma16(short8 a, short8 b, f32x4 c){
  return __builtin_amdgcn_mfma_f32_16x16x32_bf16(a, b, c, 0, 0, 0);
}

// ---------------------------------------------------------------------------
// Weight prep: wq_t/wk_t[col][d] bf16 (col = h*64+n).
// ---------------------------------------------------------------------------
__global__ __launch_bounds__(256) void prep_w(const float* __restrict__ Wq,
    const float* __restrict__ Wk,
    unsigned short* __restrict__ wq_t, unsigned short* __restrict__ wk_t){
  int i = blockIdx.x*256 + threadIdx.x;
  if (i < 512*512){
    int col = i >> 9, d = i & 511;
    int src = (col >> 6)*(512*64) + d*64 + (col & 63);
    wq_t[i] = f2bf(Wq[src]);
    wk_t[i] = f2bf(Wk[src]);
  }
}

// ---------------------------------------------------------------------------
// q/k f32 -> bf16 once (identical f2bf rounding as the old in-proj convert).
// grid 4096: first 2048 blocks convert q, rest convert k. 8 elems/thread.
// ---------------------------------------------------------------------------
__global__ __launch_bounds__(256) void conv_bf16(const float* __restrict__ q,
    const float* __restrict__ k, unsigned short* __restrict__ qbf,
    unsigned short* __restrict__ kbf){
  int blk = blockIdx.x;
  const float* src = (blk < 2048) ? q : k;
  unsigned short* dst = (blk < 2048) ? qbf : kbf;
  size_t off = ((size_t)(blk & 2047)*256 + threadIdx.x)*8;
  f32x4 f0 = *(const f32x4*)(src + off);
  f32x4 f1 = *(const f32x4*)(src + off + 4);
  ushort8 o;
  o[0]=f2bf(f0[0]); o[1]=f2bf(f0[1]); o[2]=f2bf(f0[2]); o[3]=f2bf(f0[3]);
  o[4]=f2bf(f1[0]); o[5]=f2bf(f1[1]); o[6]=f2bf(f1[2]); o[7]=f2bf(f1[3]);
  *(ushort8*)(dst + off) = o;
}

// ---------------------------------------------------------------------------
// zero macc: 512 blocks x 256 threads x 4 floats = 524,288 floats (exact).
// ---------------------------------------------------------------------------
__global__ __launch_bounds__(256) void zero_macc(float* __restrict__ macc){
  f32x4 z = {0.f,0.f,0.f,0.f};
  *(f32x4*)(macc + ((size_t)blockIdx.x*256 + threadIdx.x)*4) = z;
}

// ---------------------------------------------------------------------------
// Projection GEMM for Q/K (bf16 input): out[h][b][s][n] = bf16(A@W[h])
// Same fragment mappings as validated R3/R6; A loads are now ushort8.
// ---------------------------------------------------------------------------
__global__ __launch_bounds__(256) void proj_qk(const unsigned short* __restrict__ A,
    const unsigned short* __restrict__ Wt, unsigned short* __restrict__ outb){
  const int m0 = blockIdx.x*64;
  const int h  = blockIdx.y;
  __shared__ alignas(16) unsigned short Alds[64][40];
  __shared__ alignas(16) unsigned short Wlds[64][40];
  const int t = threadIdx.x, w = t>>6, l = t&63;
  const int srow = t>>2, sk0 = (t&3)*8;
  f32x4 acc[4] = {{0,0,0,0},{0,0,0,0},{0,0,0,0},{0,0,0,0}};
  for (int ks=0; ks<512; ks+=32){
    ushort8 av  = *(const ushort8*)(A + (size_t)(m0+srow)*512 + ks + sk0);
    ushort8 wv8 = *(const ushort8*)(Wt + (size_t)(h*64+srow)*512 + ks + sk0);
    __syncthreads();
    *(ushort8*)&Alds[srow][sk0] = av;
    *(ushort8*)&Wlds[srow][sk0] = wv8;
    __syncthreads();
    short8 a = *(const short8*)&Alds[w*16 + (l&15)][(l>>4)*8];
    #pragma unroll
    for (int nt=0; nt<4; nt++){
      short8 b = *(const short8*)&Wlds[nt*16 + (l&15)][(l>>4)*8];
      acc[nt] = mfma16(a, b, acc[nt]);
    }
  }
  #pragma unroll
  for (int nt=0; nt<4; nt++){
    #pragma unroll
    for (int r=0; r<4; r++){
      int m = m0 + w*16 + (l>>4)*4 + r;
      int b_ = m >> 11, s_ = m & 2047;
      outb[(((size_t)(h*NB + b_)*SS + s_)<<6) + nt*16 + (l&15)] = f2bf(acc[nt][r]);
    }
  }
}

// ---------------------------------------------------------------------------
// vs + transpose fused: vst[b][dv][s] = bf16( v[b,s,:] @ Wv )  (same math as
// validated vs_f32 + transpose_v; LDS transpose epilogue, s16x4 stores).
// ---------------------------------------------------------------------------
__global__ __launch_bounds__(256) void vs_fused(const float* __restrict__ v,
    const float* __restrict__ Wv, unsigned short* __restrict__ vst){
  __shared__ float vrow[4][512];
  __shared__ float vtile[4][64];
  const int t = threadIdx.x;
  const int M = blockIdx.x*4;   // global row in [0,8192)
  for (int i = t; i < 4*512; i += 256)
    vrow[i>>9][i&511] = v[(size_t)(M + (i>>9))*512 + (i&511)];
  __syncthreads();
  const int r = t>>6, dv = t&63;
  float acc = 0.f;
  for (int d = 0; d < 512; d++)
    acc += vrow[r][d] * Wv[d*64 + dv];
  vtile[r][dv] = acc;
  __syncthreads();
  if (t < 64){
    s16x4 o;
    o[0] = (short)f2bf(vtile[0][t]);
    o[1] = (short)f2bf(vtile[1][t]);
    o[2] = (short)f2bf(vtile[2][t]);
    o[3] = (short)f2bf(vtile[3][t]);
    int b_ = M >> 11, s0 = M & 2047;
    *(s16x4*)(vst + ((size_t)(b_*64 + t))*2048 + s0) = o;
  }
}

// ---------------------------------------------------------------------------
// Fused attention, K-tile = 128 (half the barriers of R8).  Identical float
// sequence: sub-tile 0 then 1 preserves the original kt-64 column order.
// ---------------------------------------------------------------------------
__global__ __launch_bounds__(256) void attn_fused(const unsigned short* __restrict__ qsb,
    const unsigned short* __restrict__ ksb, const unsigned short* __restrict__ vstb,
    float* __restrict__ attn, float* __restrict__ macc){
  const int q0 = blockIdx.x*64, b_ = blockIdx.y, h = blockIdx.z;
  __shared__ alignas(16) unsigned short Klds[128][72];
  __shared__ alignas(16) unsigned short Vlds[64][136];   // [dv][k_local 0..127]
  __shared__ alignas(16) unsigned short Plds[4][16][72];
  const int t = threadIdx.x, w = t>>6, l = t&63;
  const unsigned short* qsrc = qsb + (((size_t)(h*NB + b_)*SS + q0)<<6);
  const unsigned short* ksrc = ksb + (((size_t)(h*NB + b_)*SS)<<6);
  const unsigned short* vsrc = vstb + (size_t)b_*64*2048;

  // K staging map: 128 rows x 64 cols, 4 x ushort8 per thread
  const int krow = t>>1, kc = (t&1)*32;
  // V staging map: 64 rows x 128 cols, 4 x ushort8 per thread
  const int vrow = t>>2, vc = (t&3)*32;

  // Q fragments in registers
  short8 a0 = *(const short8*)(qsrc + (size_t)(w*16 + (l&15))*64 + (l>>4)*8);
  short8 a1 = *(const short8*)(qsrc + (size_t)(w*16 + (l&15))*64 + 32 + (l>>4)*8);

  // ---- loop 1: row sums of exp(score*scale) ----
  float rsum[4] = {0.f,0.f,0.f,0.f};
  for (int kt=0; kt<16; kt++){
    const unsigned short* kro = ksrc + ((size_t)(kt*128 + krow)<<6) + kc;
    ushort8 k0 = *(const ushort8*)(kro);
    ushort8 k1 = *(const ushort8*)(kro + 8);
    ushort8 k2 = *(const ushort8*)(kro + 16);
    ushort8 k3 = *(const ushort8*)(kro + 24);
    __syncthreads();
    *(ushort8*)&Klds[krow][kc]    = k0;  *(ushort8*)&Klds[krow][kc+8]  = k1;
    *(ushort8*)&Klds[krow][kc+16] = k2;  *(ushort8*)&Klds[krow][kc+24] = k3;
    __syncthreads();
    #pragma unroll
    for (int sub=0; sub<2; sub++){
      #pragma unroll
      for (int nt=0; nt<4; nt++){
        short8 b0 = *(const short8*)&Klds[sub*64 + nt*16 + (l&15)][(l>>4)*8];
        short8 b1 = *(const short8*)&Klds[sub*64 + nt*16 + (l&15)][32 + (l>>4)*8];
        f32x4 acc = {0.f,0.f,0.f,0.f};
        acc = mfma16(a0, b0, acc);
        acc = mfma16(a1, b1, acc);
        #pragma unroll
        for (int r=0; r<4; r++) rsum[r] += __expf(acc[r]*0.125f);
      }
    }
  }
  float ri[4];
  #pragma unroll
  for (int r=0; r<4; r++){
    float v = rsum[r];
    v += __shfl_xor(v, 1); v += __shfl_xor(v, 2);
    v += __shfl_xor(v, 4); v += __shfl_xor(v, 8);
    ri[r] = 1.0f / v;
  }

  // ---- loop 2: normalized attn writes + PV accumulate ----
  f32x4 occ[4] = {{0,0,0,0},{0,0,0,0},{0,0,0,0},{0,0,0,0}};
  float* arow = attn + (size_t)(h*NB + b_)*SS*SS + (size_t)q0*SS;
  for (int kt=0; kt<16; kt++){
    const unsigned short* kro = ksrc + ((size_t)(kt*128 + krow)<<6) + kc;
    ushort8 k0 = *(const ushort8*)(kro);
    ushort8 k1 = *(const ushort8*)(kro + 8);
    ushort8 k2 = *(const ushort8*)(kro + 16);
    ushort8 k3 = *(const ushort8*)(kro + 24);
    const unsigned short* vro = vsrc + (size_t)vrow*2048 + kt*128 + vc;
    ushort8 v0 = *(const ushort8*)(vro);
    ushort8 v1 = *(const ushort8*)(vro + 8);
    ushort8 v2 = *(const ushort8*)(vro + 16);
    ushort8 v3 = *(const ushort8*)(vro + 24);
    __syncthreads();   // prev iteration's LDS reads complete
    *(ushort8*)&Klds[krow][kc]    = k0;  *(ushort8*)&Klds[krow][kc+8]  = k1;
    *(ushort8*)&Klds[krow][kc+16] = k2;  *(ushort8*)&Klds[krow][kc+24] = k3;
    *(ushort8*)&Vlds[vrow][vc]    = v0;  *(ushort8*)&Vlds[vrow][vc+8]  = v1;
    *(ushort8*)&Vlds[vrow][vc+16] = v2;  *(ushort8*)&Vlds[vrow][vc+24] = v3;
    __syncthreads();   // tiles staged
    #pragma unroll
    for (int sub=0; sub<2; sub++){
      #pragma unroll
      for (int nt=0; nt<4; nt++){
        short8 b0 = *(const short8*)&Klds[sub*64 + nt*16 + (l&15)][(l>>4)*8];
        short8 b1 = *(const short8*)&Klds[sub*64 + nt*16 + (l&15)][32 + (l>>4)*8];
        f32x4 acc = {0.f,0.f,0.f,0.f};
        acc = mfma16(a0, b0, acc);
        acc = mfma16(a1, b1, acc);
        #pragma unroll
        for (int r=0; r<4; r++){
          float p = __expf(acc[r]*0.125f) * ri[r];
          arow[(size_t)(w*16 + (l>>4)*4 + r)*SS + kt*128 + sub*64 + nt*16 + (l&15)] = p;
          Plds[w][(l>>4)*4 + r][nt*16 + (l&15)] = f2bf(p);
        }
      }
      // Plds is wave-private: per-wave LDS drain orders writes vs reads.
      asm volatile("s_waitcnt lgkmcnt(0)" ::: "memory");
      __builtin_amdgcn_sched_barrier(0);
      #pragma unroll
      for (int kk=0; kk<2; kk++){
        short8 pa = *(const short8*)&Plds[w][l&15][kk*32 + (l>>4)*8];
        #pragma unroll
        for (int n2=0; n2<4; n2++){
          short8 vb = *(const short8*)&Vlds[n2*16 + (l&15)][sub*64 + kk*32 + (l>>4)*8];
          occ[n2] = mfma16(pa, vb, occ[n2]);
        }
      }
    }
  }
  #pragma unroll
  for (int n2=0; n2<4; n2++){
    #pragma unroll
    for (int r=0; r<4; r++){
      atomicAdd(macc + ((size_t)(b_*SS + q0 + w*16 + (l>>4)*4 + r)<<6) + n2*16 + (l&15),
                occ[n2][r]*0.125f);
    }
  }
}

// ---------------------------------------------------------------------------
// Final: out[b,s,:] = macc[b,s,:] @ Wo[64,512]  (validated)
// ---------------------------------------------------------------------------
__global__ __launch_bounds__(256) void final_out(const float* __restrict__ macc,
    const float* __restrict__ Wo, float* __restrict__ out){
  __shared__ alignas(16) float mlds[32][68];
  const int t = threadIdx.x;
  const int m0 = blockIdx.x*32;
  {
    int row = t>>3, k0 = (t&7)*8;
    const f32x4* src = (const f32x4*)(macc + (size_t)(m0+row)*64 + k0);
    *(f32x4*)&mlds[row][k0]   = src[0];
    *(f32x4*)&mlds[row][k0+4] = src[1];
  }
  __syncthreads();
  const int mrow = t>>3, n0 = (t&7)*64;
  f32x4 zero = {0.f,0.f,0.f,0.f};
  f32x4 a4[16];
  #pragma unroll
  for (int j=0;j<16;j++) a4[j] = zero;
  for (int k=0; k<64; k++){
    float am = mlds[mrow][k];
    const f32x4* wo4 = (const f32x4*)(Wo + (size_t)k*512 + n0);
    #pragma unroll
    for (int j=0; j<16; j++) a4[j] += am * wo4[j];
  }
  float* dst = out + (size_t)(m0+mrow)*512 + n0;
  #pragma unroll
  for (int j=0; j<16; j++) *(f32x4*)(dst + j*4) = a4[j];
}

// ---------------------------------------------------------------------------
// Scratch plan:
//   d_out head  [0 .. 16.8MB)        : qs_buf | ks_buf  (dead before final_out)
//   attn start  [0 .. 16MB of attn)  : qbf | kbf        (dead before attn_fused)
//   attn tail   [last 1MB of attn)   : wq_t | wk_t      (dead before attn_fused)
//   d_ws 3.41MB: (256K unused) | vst 1M | macc 2M
// ---------------------------------------------------------------------------
extern "C" void kernel_launch(void* const* d_in, const int* in_sizes, int n_in,
                              void* d_out, int out_size, void* d_ws, size_t ws_size,
                              hipStream_t stream){
  (void)in_sizes; (void)n_in; (void)out_size; (void)ws_size;
  const float* q  = (const float*)d_in[0];
  const float* k  = (const float*)d_in[1];
  const float* v  = (const float*)d_in[2];
  const float* Wq = (const float*)d_in[3];
  const float* Wk = (const float*)d_in[4];
  const float* Wv = (const float*)d_in[5];
  const float* Wo = (const float*)d_in[6];
  float* out  = (float*)d_out;
  float* attn = out + (size_t)NB*SS*DMODEL;   // outputs concatenated: out, attn

  unsigned short* qs_buf = (unsigned short*)d_out;
  unsigned short* ks_buf = qs_buf + (size_t)NH*NB*SS*DKK;
  unsigned short* w_tail = (unsigned short*)(attn + (size_t)NH*NB*SS*SS) - (262144 + 262144);
  unsigned short* wq_t = w_tail;
  unsigned short* wk_t = w_tail + 262144;
  unsigned short* qbf = (unsigned short*)attn;                 // 8MB
  unsigned short* kbf = qbf + (size_t)NB*SS*DMODEL;            // 8MB

  unsigned short* vst  = (unsigned short*)((char*)d_ws + 262144);   // 1,048,576 B
  float* macc          = (float*)((char*)d_ws + 1310720);           // 2,097,152 B

  prep_w<<<dim3(1024), 256, 0, stream>>>(Wq, Wk, wq_t, wk_t);
  conv_bf16<<<dim3(4096), 256, 0, stream>>>(q, k, qbf, kbf);
  zero_macc<<<dim3(512), 256, 0, stream>>>(macc);
  proj_qk<<<dim3(128, 8), 256, 0, stream>>>(qbf, wq_t, qs_buf);
  proj_qk<<<dim3(128, 8), 256, 0, stream>>>(kbf, wk_t, ks_buf);
  vs_fused<<<dim3(2048), 256, 0, stream>>>(v, Wv, vst);
  attn_fused<<<dim3(32, NB, NH), 256, 0, stream>>>(qs_buf, ks_buf, vst, attn, macc);
  final_out<<<dim3(256), 256, 0, stream>>>(macc, Wo, out);
}

// Round 11
// 394.586 us; speedup vs baseline: 1.7271x; 1.0525x over previous
//
#include <hip/hip_runtime.h>
#include <hip/hip_bf16.h>
#include <cstdint>
#include <cstddef>

#define NB 4
#define SS 2048
#define DMODEL 512
#define NH 8
#define DKK 64

typedef __attribute__((ext_vector_type(8))) short short8;
typedef __attribute__((ext_vector_type(4))) short s16x4;
typedef __attribute__((ext_vector_type(8))) unsigned short ushort8;
typedef __attribute__((ext_vector_type(4))) float f32x4;

static __device__ __forceinline__ unsigned short f2bf(float f){
  unsigned int u = __float_as_uint(f);
  u += 0x7fff + ((u >> 16) & 1);   // round-to-nearest-even
  return (unsigned short)(u >> 16);
}

static __device__ __forceinline__ f32x4 mfma16(short8 a, short8 b, f32x4 c){
  return __builtin_amdgcn_mfma_f32_16x16x32_bf16(a, b, c, 0, 0, 0);
}

// ---------------------------------------------------------------------------
// prep_all: blk<1024 -> wq/wk transpose; blk<5120 -> q/k bf16 convert;
// else zero macc.  (3 kernels merged)
// ---------------------------------------------------------------------------
__global__ __launch_bounds__(256) void prep_all(const float* __restrict__ Wq,
    const float* __restrict__ Wk, const float* __restrict__ q,
    const float* __restrict__ k, unsigned short* __restrict__ wq_t,
    unsigned short* __restrict__ wk_t, unsigned short* __restrict__ qbf,
    unsigned short* __restrict__ kbf, float* __restrict__ macc){
  int blk = blockIdx.x;
  if (blk < 1024){
    int i = blk*256 + threadIdx.x;
    int col = i >> 9, d = i & 511;
    int src = (col >> 6)*(512*64) + d*64 + (col & 63);
    wq_t[i] = f2bf(Wq[src]);
    wk_t[i] = f2bf(Wk[src]);
  } else if (blk < 5120){
    int b2 = blk - 1024;
    const float* src = (b2 < 2048) ? q : k;
    unsigned short* dst = (b2 < 2048) ? qbf : kbf;
    size_t off = ((size_t)(b2 & 2047)*256 + threadIdx.x)*8;
    f32x4 f0 = *(const f32x4*)(src + off);
    f32x4 f1 = *(const f32x4*)(src + off + 4);
    ushort8 o;
    o[0]=f2bf(f0[0]); o[1]=f2bf(f0[1]); o[2]=f2bf(f0[2]); o[3]=f2bf(f0[3]);
    o[4]=f2bf(f1[0]); o[5]=f2bf(f1[1]); o[6]=f2bf(f1[2]); o[7]=f2bf(f1[3]);
    *(ushort8*)(dst + off) = o;
  } else {
    f32x4 z = {0.f,0.f,0.f,0.f};
    *(f32x4*)(macc + ((size_t)(blk-5120)*256 + threadIdx.x)*4) = z;
  }
}

// ---------------------------------------------------------------------------
// Projection GEMM for Q and K in one launch (blockIdx.z picks input/output).
// Same fragment mappings as validated R3/R6.
// ---------------------------------------------------------------------------
__global__ __launch_bounds__(256) void proj_both(const unsigned short* __restrict__ qbf,
    const unsigned short* __restrict__ kbf, const unsigned short* __restrict__ wq_t,
    const unsigned short* __restrict__ wk_t, unsigned short* __restrict__ qs,
    unsigned short* __restrict__ ks){
  const unsigned short* A  = blockIdx.z ? kbf : qbf;
  const unsigned short* Wt = blockIdx.z ? wk_t : wq_t;
  unsigned short* outb     = blockIdx.z ? ks : qs;
  const int m0 = blockIdx.x*64;
  const int h  = blockIdx.y;
  __shared__ alignas(16) unsigned short Alds[64][40];
  __shared__ alignas(16) unsigned short Wlds[64][40];
  const int t = threadIdx.x, w = t>>6, l = t&63;
  const int srow = t>>2, sk0 = (t&3)*8;
  f32x4 acc[4] = {{0,0,0,0},{0,0,0,0},{0,0,0,0},{0,0,0,0}};
  for (int ks_=0; ks_<512; ks_+=32){
    ushort8 av  = *(const ushort8*)(A + (size_t)(m0+srow)*512 + ks_ + sk0);
    ushort8 wv8 = *(const ushort8*)(Wt + (size_t)(h*64+srow)*512 + ks_ + sk0);
    __syncthreads();
    *(ushort8*)&Alds[srow][sk0] = av;
    *(ushort8*)&Wlds[srow][sk0] = wv8;
    __syncthreads();
    short8 a = *(const short8*)&Alds[w*16 + (l&15)][(l>>4)*8];
    #pragma unroll
    for (int nt=0; nt<4; nt++){
      short8 b = *(const short8*)&Wlds[nt*16 + (l&15)][(l>>4)*8];
      acc[nt] = mfma16(a, b, acc[nt]);
    }
  }
  #pragma unroll
  for (int nt=0; nt<4; nt++){
    #pragma unroll
    for (int r=0; r<4; r++){
      int m = m0 + w*16 + (l>>4)*4 + r;
      int b_ = m >> 11, s_ = m & 2047;
      outb[(((size_t)(h*NB + b_)*SS + s_)<<6) + nt*16 + (l&15)] = f2bf(acc[nt][r]);
    }
  }
}

// ---------------------------------------------------------------------------
// vs + transpose fused (validated R10): vst[b][dv][s] = bf16( v[b,s,:] @ Wv )
// ---------------------------------------------------------------------------
__global__ __launch_bounds__(256) void vs_fused(const float* __restrict__ v,
    const float* __restrict__ Wv, unsigned short* __restrict__ vst){
  __shared__ float vrow[4][512];
  __shared__ float vtile[4][64];
  const int t = threadIdx.x;
  const int M = blockIdx.x*4;   // global row in [0,8192)
  for (int i = t; i < 4*512; i += 256)
    vrow[i>>9][i&511] = v[(size_t)(M + (i>>9))*512 + (i&511)];
  __syncthreads();
  const int r = t>>6, dv = t&63;
  float acc = 0.f;
  for (int d = 0; d < 512; d++)
    acc += vrow[r][d] * Wv[d*64 + dv];
  vtile[r][dv] = acc;
  __syncthreads();
  if (t < 64){
    s16x4 o;
    o[0] = (short)f2bf(vtile[0][t]);
    o[1] = (short)f2bf(vtile[1][t]);
    o[2] = (short)f2bf(vtile[2][t]);
    o[3] = (short)f2bf(vtile[3][t]);
    int b_ = M >> 11, s0 = M & 2047;
    *(s16x4*)(vst + ((size_t)(b_*64 + t))*2048 + s0) = o;
  }
}

// ---------------------------------------------------------------------------
// Fused attention with SWAPPED QK^T: mfma(K,Q) puts 4 consecutive s-values
// per lane (C-layout col=lane&15 -> q, row -> s), enabling f32x4 attn stores,
// b64 Plds writes, and a 2-shuffle row reduce with scalar ri.
// PV path (P as A-operand from Plds, V from Vlds) byte-identical to validated.
// ---------------------------------------------------------------------------
__global__ __launch_bounds__(256) void attn_fused(const unsigned short* __restrict__ qsb,
    const unsigned short* __restrict__ ksb, const unsigned short* __restrict__ vstb,
    float* __restrict__ attn, float* __restrict__ macc){
  const int q0 = blockIdx.x*64, b_ = blockIdx.y, h = blockIdx.z;
  __shared__ alignas(16) unsigned short Klds[128][72];
  __shared__ alignas(16) unsigned short Vlds[64][136];   // [dv][k_local 0..127]
  __shared__ alignas(16) unsigned short Plds[4][16][72]; // [wave][q_local][s]
  const int t = threadIdx.x, w = t>>6, l = t&63;
  const unsigned short* qsrc = qsb + (((size_t)(h*NB + b_)*SS + q0)<<6);
  const unsigned short* ksrc = ksb + (((size_t)(h*NB + b_)*SS)<<6);
  const unsigned short* vsrc = vstb + (size_t)b_*64*2048;

  const int krow = t>>1, kc = (t&1)*32;   // K staging: 128 x 64
  const int vrow = t>>2, vc = (t&3)*32;   // V staging: 64 x 128

  // Q fragments (per-lane formula identical for A- and B-operand use)
  short8 a0 = *(const short8*)(qsrc + (size_t)(w*16 + (l&15))*64 + (l>>4)*8);
  short8 a1 = *(const short8*)(qsrc + (size_t)(w*16 + (l&15))*64 + 32 + (l>>4)*8);

  // ---- loop 1: row sums of exp(score*scale), swapped operands ----
  float rsum = 0.f;
  for (int kt=0; kt<16; kt++){
    const unsigned short* kro = ksrc + ((size_t)(kt*128 + krow)<<6) + kc;
    ushort8 k0 = *(const ushort8*)(kro);
    ushort8 k1 = *(const ushort8*)(kro + 8);
    ushort8 k2 = *(const ushort8*)(kro + 16);
    ushort8 k3 = *(const ushort8*)(kro + 24);
    __syncthreads();
    *(ushort8*)&Klds[krow][kc]    = k0;  *(ushort8*)&Klds[krow][kc+8]  = k1;
    *(ushort8*)&Klds[krow][kc+16] = k2;  *(ushort8*)&Klds[krow][kc+24] = k3;
    __syncthreads();
    #pragma unroll
    for (int sub=0; sub<2; sub++){
      #pragma unroll
      for (int nt=0; nt<4; nt++){
        short8 b0 = *(const short8*)&Klds[sub*64 + nt*16 + (l&15)][(l>>4)*8];
        short8 b1 = *(const short8*)&Klds[sub*64 + nt*16 + (l&15)][32 + (l>>4)*8];
        f32x4 acc = {0.f,0.f,0.f,0.f};
        acc = mfma16(b0, a0, acc);   // swapped: A=K, B=Q -> C[s][q]
        acc = mfma16(b1, a1, acc);
        #pragma unroll
        for (int r=0; r<4; r++) rsum += __expf(acc[r]*0.125f);
      }
    }
  }
  rsum += __shfl_xor(rsum, 16);
  rsum += __shfl_xor(rsum, 32);
  const float ri = 1.0f / rsum;    // per-lane q = w*16 + (l&15)

  // ---- loop 2: f32x4 attn stores + PV accumulate ----
  f32x4 occ[4] = {{0,0,0,0},{0,0,0,0},{0,0,0,0},{0,0,0,0}};
  float* arow = attn + (size_t)(h*NB + b_)*SS*SS + (size_t)q0*SS;
  float* const myrow = arow + (size_t)(w*16 + (l&15))*SS + (l>>4)*4;
  for (int kt=0; kt<16; kt++){
    const unsigned short* kro = ksrc + ((size_t)(kt*128 + krow)<<6) + kc;
    ushort8 k0 = *(const ushort8*)(kro);
    ushort8 k1 = *(const ushort8*)(kro + 8);
    ushort8 k2 = *(const ushort8*)(kro + 16);
    ushort8 k3 = *(const ushort8*)(kro + 24);
    const unsigned short* vro = vsrc + (size_t)vrow*2048 + kt*128 + vc;
    ushort8 v0 = *(const ushort8*)(vro);
    ushort8 v1 = *(const ushort8*)(vro + 8);
    ushort8 v2 = *(const ushort8*)(vro + 16);
    ushort8 v3 = *(const ushort8*)(vro + 24);
    __syncthreads();   // prev iteration's LDS reads complete
    *(ushort8*)&Klds[krow][kc]    = k0;  *(ushort8*)&Klds[krow][kc+8]  = k1;
    *(ushort8*)&Klds[krow][kc+16] = k2;  *(ushort8*)&Klds[krow][kc+24] = k3;
    *(ushort8*)&Vlds[vrow][vc]    = v0;  *(ushort8*)&Vlds[vrow][vc+8]  = v1;
    *(ushort8*)&Vlds[vrow][vc+16] = v2;  *(ushort8*)&Vlds[vrow][vc+24] = v3;
    __syncthreads();   // tiles staged
    #pragma unroll
    for (int sub=0; sub<2; sub++){
      #pragma unroll
      for (int nt=0; nt<4; nt++){
        short8 b0 = *(const short8*)&Klds[sub*64 + nt*16 + (l&15)][(l>>4)*8];
        short8 b1 = *(const short8*)&Klds[sub*64 + nt*16 + (l&15)][32 + (l>>4)*8];
        f32x4 acc = {0.f,0.f,0.f,0.f};
        acc = mfma16(b0, a0, acc);   // swapped
        acc = mfma16(b1, a1, acc);
        f32x4 pr;
        s16x4 pb;
        #pragma unroll
        for (int r=0; r<4; r++){
          float p = __expf(acc[r]*0.125f) * ri;
          pr[r] = p;
          pb[r] = (short)f2bf(p);
        }
        *(f32x4*)(myrow + kt*128 + sub*64 + nt*16) = pr;             // dwordx4
        *(s16x4*)&Plds[w][l&15][nt*16 + (l>>4)*4] = pb;              // b64
      }
      // Plds is wave-private: per-wave LDS drain orders writes vs reads.
      asm volatile("s_waitcnt lgkmcnt(0)" ::: "memory");
      __builtin_amdgcn_sched_barrier(0);
      #pragma unroll
      for (int kk=0; kk<2; kk++){
        short8 pa = *(const short8*)&Plds[w][l&15][kk*32 + (l>>4)*8];
        #pragma unroll
        for (int n2=0; n2<4; n2++){
          short8 vb = *(const short8*)&Vlds[n2*16 + (l&15)][sub*64 + kk*32 + (l>>4)*8];
          occ[n2] = mfma16(pa, vb, occ[n2]);
        }
      }
    }
  }
  #pragma unroll
  for (int n2=0; n2<4; n2++){
    #pragma unroll
    for (int r=0; r<4; r++){
      atomicAdd(macc + ((size_t)(b_*SS + q0 + w*16 + (l>>4)*4 + r)<<6) + n2*16 + (l&15),
                occ[n2][r]*0.125f);
    }
  }
}

// ---------------------------------------------------------------------------
// Final: out[b,s,:] = macc[b,s,:] @ Wo[64,512]  (validated)
// ---------------------------------------------------------------------------
__global__ __launch_bounds__(256) void final_out(const float* __restrict__ macc,
    const float* __restrict__ Wo, float* __restrict__ out){
  __shared__ alignas(16) float mlds[32][68];
  const int t = threadIdx.x;
  const int m0 = blockIdx.x*32;
  {
    int row = t>>3, k0 = (t&7)*8;
    const f32x4* src = (const f32x4*)(macc + (size_t)(m0+row)*64 + k0);
    *(f32x4*)&mlds[row][k0]   = src[0];
    *(f32x4*)&mlds[row][k0+4] = src[1];
  }
  __syncthreads();
  const int mrow = t>>3, n0 = (t&7)*64;
  f32x4 zero = {0.f,0.f,0.f,0.f};
  f32x4 a4[16];
  #pragma unroll
  for (int j=0;j<16;j++) a4[j] = zero;
  for (int k=0; k<64; k++){
    float am = mlds[mrow][k];
    const f32x4* wo4 = (const f32x4*)(Wo + (size_t)k*512 + n0);
    #pragma unroll
    for (int j=0; j<16; j++) a4[j] += am * wo4[j];
  }
  float* dst = out + (size_t)(m0+mrow)*512 + n0;
  #pragma unroll
  for (int j=0; j<16; j++) *(f32x4*)(dst + j*4) = a4[j];
}

// ---------------------------------------------------------------------------
// Scratch plan:
//   d_out head  [0 .. 16.8MB)        : qs_buf | ks_buf  (dead before final_out)
//   attn start  [0 .. 16MB of attn)  : qbf | kbf        (dead before attn_fused)
//   attn tail   [last 1MB of attn)   : wq_t | wk_t      (dead before attn_fused)
//   d_ws 3.41MB: (256K unused) | vst 1M | macc 2M
// ---------------------------------------------------------------------------
extern "C" void kernel_launch(void* const* d_in, const int* in_sizes, int n_in,
                              void* d_out, int out_size, void* d_ws, size_t ws_size,
                              hipStream_t stream){
  (void)in_sizes; (void)n_in; (void)out_size; (void)ws_size;
  const float* q  = (const float*)d_in[0];
  const float* k  = (const float*)d_in[1];
  const float* v  = (const float*)d_in[2];
  const float* Wq = (const float*)d_in[3];
  const float* Wk = (const float*)d_in[4];
  const float* Wv = (const float*)d_in[5];
  const float* Wo = (const float*)d_in[6];
  float* out  = (float*)d_out;
  float* attn = out + (size_t)NB*SS*DMODEL;   // outputs concatenated: out, attn

  unsigned short* qs_buf = (unsigned short*)d_out;
  unsigned short* ks_buf = qs_buf + (size_t)NH*NB*SS*DKK;
  unsigned short* w_tail = (unsigned short*)(attn + (size_t)NH*NB*SS*SS) - (262144 + 262144);
  unsigned short* wq_t = w_tail;
  unsigned short* wk_t = w_tail + 262144;
  unsigned short* qbf = (unsigned short*)attn;                 // 8MB
  unsigned short* kbf = qbf + (size_t)NB*SS*DMODEL;            // 8MB

  unsigned short* vst  = (unsigned short*)((char*)d_ws + 262144);   // 1,048,576 B
  float* macc          = (float*)((char*)d_ws + 1310720);           // 2,097,152 B

  prep_all<<<dim3(5632), 256, 0, stream>>>(Wq, Wk, q, k, wq_t, wk_t, qbf, kbf, macc);
  proj_both<<<dim3(128, 8, 2), 256, 0, stream>>>(qbf, kbf, wq_t, wk_t, qs_buf, ks_buf);
  vs_fused<<<dim3(2048), 256, 0, stream>>>(v, Wv, vst);
  attn_fused<<<dim3(32, NB, NH), 256, 0, stream>>>(qs_buf, ks_buf, vst, attn, macc);
  final_out<<<dim3(256), 256, 0, stream>>>(macc, Wo, out);
}